// Round 13
// baseline (224.100 us; speedup 1.0000x reference)
//
#include <hip/hip_runtime.h>
#include <hip/hip_bf16.h>
#include <stdint.h>

#define HIDDEN 1024
#define HEADS 16
#define HD 64
#define BATCH 8
#define SEQ 1024
#define MTOT (BATCH*SEQ)   // 8192 rows total

typedef __attribute__((ext_vector_type(4))) float  f32x4;
typedef __attribute__((ext_vector_type(4))) float  float4v;
typedef __attribute__((ext_vector_type(8))) short  s16x8;
typedef __attribute__((ext_vector_type(4))) short  s16x4;
typedef __attribute__((ext_vector_type(4))) unsigned int u32x4;
typedef __bf16 bf16x8 __attribute__((ext_vector_type(8)));

// log2(e) / sqrt(HEAD_DIM)
#define QSCALE 0.18033688011112042f

__device__ __forceinline__ short f2bf(float f) {
  uint32_t u = __builtin_bit_cast(uint32_t, f);
  u += 0x7FFFu + ((u >> 16) & 1u);          // RNE to bf16
  return (short)(u >> 16);
}
__device__ __forceinline__ bf16x8 asbf(s16x8 v) {
  return __builtin_bit_cast(bf16x8, v);
}

// ---- DPP 16-lane reductions (VALU only) -----------------------------------
__device__ __forceinline__ float dpp_fmax16(float x) {
  int t;
  t = __builtin_amdgcn_update_dpp(0, __builtin_bit_cast(int, x), 0xB1, 0xF, 0xF, true);
  x = fmaxf(x, __builtin_bit_cast(float, t));
  t = __builtin_amdgcn_update_dpp(0, __builtin_bit_cast(int, x), 0x4E, 0xF, 0xF, true);
  x = fmaxf(x, __builtin_bit_cast(float, t));
  t = __builtin_amdgcn_update_dpp(0, __builtin_bit_cast(int, x), 0x141, 0xF, 0xF, true);
  x = fmaxf(x, __builtin_bit_cast(float, t));
  t = __builtin_amdgcn_update_dpp(0, __builtin_bit_cast(int, x), 0x140, 0xF, 0xF, true);
  x = fmaxf(x, __builtin_bit_cast(float, t));
  return x;
}
__device__ __forceinline__ float dpp_fadd16(float x) {
  int t;
  t = __builtin_amdgcn_update_dpp(0, __builtin_bit_cast(int, x), 0xB1, 0xF, 0xF, true);
  x += __builtin_bit_cast(float, t);
  t = __builtin_amdgcn_update_dpp(0, __builtin_bit_cast(int, x), 0x4E, 0xF, 0xF, true);
  x += __builtin_bit_cast(float, t);
  t = __builtin_amdgcn_update_dpp(0, __builtin_bit_cast(int, x), 0x141, 0xF, 0xF, true);
  x += __builtin_bit_cast(float, t);
  t = __builtin_amdgcn_update_dpp(0, __builtin_bit_cast(int, x), 0x140, 0xF, 0xF, true);
  x += __builtin_bit_cast(float, t);
  return x;
}

// global -> LDS direct DMA, 16 B per lane.
typedef const __attribute__((address_space(1))) void* gvp;
typedef __attribute__((address_space(3)))       void* lvp;
__device__ __forceinline__ void gl_lds16(const void* g, const void* ldsbase) {
  __builtin_amdgcn_global_load_lds((gvp)(uintptr_t)g,
                                   (lvp)(uintptr_t)(uint32_t)(uintptr_t)ldsbase,
                                   16, 0, 0);
}

// ---------------------------------------------------------------------------
// fp32 -> bf16 converters
// ---------------------------------------------------------------------------
__global__ __launch_bounds__(256) void cvt_x(const float* __restrict__ src,
                                             short* __restrict__ dst) {
  int i = blockIdx.x * 256 + threadIdx.x;
  float4v a = *(const float4v*)(src + (size_t)i * 8);
  float4v b = *(const float4v*)(src + (size_t)i * 8 + 4);
  s16x8 o = { f2bf(a.x), f2bf(a.y), f2bf(a.z), f2bf(a.w),
              f2bf(b.x), f2bf(b.y), f2bf(b.z), f2bf(b.w) };
  *(s16x8*)(dst + (size_t)i * 8) = o;
}

__global__ __launch_bounds__(256) void cvt_w(const float* __restrict__ s0,
                                             const float* __restrict__ s1,
                                             const float* __restrict__ s2,
                                             const float* __restrict__ s3,
                                             short* __restrict__ dst) {
  int z = blockIdx.y;
  const float* src = (z == 0) ? s0 : (z == 1) ? s1 : (z == 2) ? s2 : s3;
  int i = blockIdx.x * 256 + threadIdx.x;
  float4v a = *(const float4v*)(src + (size_t)i * 8);
  float4v b = *(const float4v*)(src + (size_t)i * 8 + 4);
  s16x8 o = { f2bf(a.x), f2bf(a.y), f2bf(a.z), f2bf(a.w),
              f2bf(b.x), f2bf(b.y), f2bf(b.z), f2bf(b.w) };
  *(s16x8*)(dst + (size_t)z * 1048576 + (size_t)i * 8) = o;
}

// ---------------------------------------------------------------------------
// V transpose: Vb[s][h*64+d] -> Vt[(b*16+h)*64+d][s], with flash's k-block
// swizzle (block ^= d&7) pre-applied per 64-k tile. Coalesced both sides.
// ---------------------------------------------------------------------------
__global__ __launch_bounds__(256) void vtrans(const short* __restrict__ Vb,
                                              short* __restrict__ Vt) {
  __shared__ short lt[64 * 64];
  const int t = threadIdx.x;
  const int kt0 = blockIdx.x, h = blockIdx.y, b = blockIdx.z;
  const short* src = Vb + ((size_t)(b * 1024 + kt0 * 64)) * 1024 + h * 64;

  #pragma unroll
  for (int i = 0; i < 2; i++) {
    int c = t + i * 256;
    int s = c >> 3, dc = c & 7;
    s16x8 v = *(const s16x8*)(src + (size_t)s * 1024 + dc * 8);
    int dcp = dc ^ (s & 7) ^ ((s >> 3) & 7);
    *(s16x8*)(&lt[s * 64 + dcp * 8]) = v;
  }
  __syncthreads();

  short* dst = Vt + ((size_t)(b * 16 + h) * 64) * 1024 + kt0 * 64;
  #pragma unroll
  for (int i = 0; i < 2; i++) {
    int c = t + i * 256;
    int d = c >> 3, kc = c & 7;
    s16x8 o;
    #pragma unroll
    for (int j = 0; j < 8; j++) {
      int s = kc * 8 + j;
      o[j] = lt[s * 64 + (((d >> 3) ^ j ^ kc) * 8) + (d & 7)];
    }
    *(s16x8*)(dst + (size_t)d * 1024 + (kc ^ (d & 7)) * 8) = o;
  }
}

// ---------------------------------------------------------------------------
// Fast GEMM (bf16 A and W from ws): C = (A @ W^T + bias) * scale
// v13: 8 waves (512 thr), 128x128 tile, BK=32. Each wave owns a 64x32
// sub-tile (wr=w>>2, wc=w&3; acc[4][2]; 8 MFMA/K-step). 16 waves/CU for
// barrier-drain coverage. Staging: exactly one 16B DMA chunk per thread
// per matrix, same linear-dest pattern as proven 4-wave version.
// CMODE: 0 = f32 out, 1 = bf16 out, 2 = bf16 out with K-col swizzle
// ---------------------------------------------------------------------------
template<int CMODE>
__global__ __launch_bounds__(512, 2) void gemm_bf16_dma(
    const short* __restrict__ A, const short* __restrict__ Wb,
    const float* __restrict__ bias, void* __restrict__ Cv, float scale)
{
  __shared__ short Alds[128 * 32];
  __shared__ short Blds[128 * 32];

  const int t  = threadIdx.x;
  const int w  = t >> 6, l = t & 63, g = l >> 4, ln = l & 15;
  const int wr = w >> 2, wc = w & 3;
  const int m0 = blockIdx.x * 128, n0 = blockIdx.y * 128;

  // staging chunk (one per thread per matrix): row = t>>2, col8 = t&3
  const int srow = t >> 2, scol8 = t & 3;

  f32x4 acc[4][2];
  #pragma unroll
  for (int i = 0; i < 4; i++)
    #pragma unroll
    for (int j = 0; j < 2; j++) acc[i][j] = (f32x4)0.0f;

  for (int k0 = 0; k0 < 1024; k0 += 32) {
    gl_lds16(A  + (size_t)(m0 + srow) * 1024 + k0 + scol8 * 8,
             &Alds[(w * 64) * 8]);
    gl_lds16(Wb + (size_t)(n0 + srow) * 1024 + k0 + scol8 * 8,
             &Blds[(w * 64) * 8]);
    __syncthreads();

    s16x8 af[4], bfr[2];
    #pragma unroll
    for (int mf = 0; mf < 4; mf++)
      af[mf] = *(const s16x8*)(&Alds[(wr * 64 + mf * 16 + ln) * 32 + g * 8]);
    #pragma unroll
    for (int nf = 0; nf < 2; nf++)
      bfr[nf] = *(const s16x8*)(&Blds[(wc * 32 + nf * 16 + ln) * 32 + g * 8]);

    __builtin_amdgcn_s_setprio(1);
    #pragma unroll
    for (int mf = 0; mf < 4; mf++)
      #pragma unroll
      for (int nf = 0; nf < 2; nf++)
        acc[mf][nf] = __builtin_amdgcn_mfma_f32_16x16x32_bf16(
            asbf(af[mf]), asbf(bfr[nf]), acc[mf][nf], 0, 0, 0);
    __builtin_amdgcn_s_setprio(0);
    __syncthreads();
  }

  float bv[2];
  #pragma unroll
  for (int nf = 0; nf < 2; nf++) bv[nf] = bias[n0 + wc * 32 + nf * 16 + ln];
  #pragma unroll
  for (int mf = 0; mf < 4; mf++)
    #pragma unroll
    for (int nf = 0; nf < 2; nf++)
      #pragma unroll
      for (int r = 0; r < 4; r++) {
        float vv = (acc[mf][nf][r] + bv[nf]) * scale;
        size_t idx = (size_t)(m0 + wr * 64 + mf * 16 + g * 4 + r) * 1024
                   + n0 + wc * 32 + nf * 16 + ln;
        if constexpr (CMODE == 0) ((float*)Cv)[idx] = vv;
        else if constexpr (CMODE == 1) ((short*)Cv)[idx] = f2bf(vv);
        else {
          size_t idxs = idx ^ (size_t)(((g * 4 + r) & 7) * 8);  // col^8*(row&7)
          ((short*)Cv)[idxs] = f2bf(vv);
        }
      }
}

// ---------------------------------------------------------------------------
// Fallback GEMM (reg-staged conversion), C = (A @ W^T + bias) * scale
// ---------------------------------------------------------------------------
template<bool A_IS_BF16, bool OUT_IS_F32>
__global__ __launch_bounds__(256, 2) void gemm_bt_bias(
    const void* __restrict__ Av, const float* __restrict__ W,
    const float* __restrict__ bias, void* __restrict__ Cv, float scale)
{
  __shared__ short Alds[128 * 32];
  __shared__ short Blds[128 * 32];

  const int t  = threadIdx.x;
  const int w  = t >> 6, l = t & 63, g = l >> 4, ln = l & 15;
  const int wr = w >> 1, wc = w & 1;
  const int m0 = blockIdx.x * 128, n0 = blockIdx.y * 128;

  f32x4 acc[4][4];
  #pragma unroll
  for (int i = 0; i < 4; i++)
    #pragma unroll
    for (int j = 0; j < 4; j++) acc[i][j] = (f32x4)0.0f;

  const float* Af = (const float*)Av;
  const short* Ab = (const short*)Av;

  for (int k0 = 0; k0 < 1024; k0 += 32) {
    if constexpr (!A_IS_BF16) {
      #pragma unroll
      for (int i = 0; i < 4; i++) {
        int c = i * 256 + t;
        int row = c >> 3, c4 = c & 7;
        float4v v = *(const float4v*)(Af + (size_t)(m0 + row) * 1024 + k0 + c4 * 4);
        s16x4 p = { f2bf(v.x), f2bf(v.y), f2bf(v.z), f2bf(v.w) };
        *(s16x4*)(&Alds[row * 32 + c4 * 4]) = p;
      }
    } else {
      #pragma unroll
      for (int i = 0; i < 2; i++) {
        int c = i * 256 + t;
        int row = c >> 2, c8 = c & 3;
        *(s16x8*)(&Alds[row * 32 + c8 * 8]) =
            *(const s16x8*)(Ab + (size_t)(m0 + row) * 1024 + k0 + c8 * 8);
      }
    }
    #pragma unroll
    for (int i = 0; i < 4; i++) {
      int c = i * 256 + t;
      int row = c >> 3, c4 = c & 7;
      float4v v = *(const float4v*)(W + (size_t)(n0 + row) * 1024 + k0 + c4 * 4);
      s16x4 p = { f2bf(v.x), f2bf(v.y), f2bf(v.z), f2bf(v.w) };
      *(s16x4*)(&Blds[row * 32 + c4 * 4]) = p;
    }
    __syncthreads();

    s16x8 af[4], bfr[4];
    #pragma unroll
    for (int mf = 0; mf < 4; mf++)
      af[mf] = *(const s16x8*)(&Alds[(wr * 64 + mf * 16 + ln) * 32 + g * 8]);
    #pragma unroll
    for (int nf = 0; nf < 4; nf++)
      bfr[nf] = *(const s16x8*)(&Blds[(wc * 64 + nf * 16 + ln) * 32 + g * 8]);

    #pragma unroll
    for (int mf = 0; mf < 4; mf++)
      #pragma unroll
      for (int nf = 0; nf < 4; nf++)
        acc[mf][nf] = __builtin_amdgcn_mfma_f32_16x16x32_bf16(
            asbf(af[mf]), asbf(bfr[nf]), acc[mf][nf], 0, 0, 0);
    __syncthreads();
  }

  float bv[4];
  #pragma unroll
  for (int nf = 0; nf < 4; nf++) bv[nf] = bias[n0 + wc * 64 + nf * 16 + ln];
  #pragma unroll
  for (int mf = 0; mf < 4; mf++)
    #pragma unroll
    for (int nf = 0; nf < 4; nf++)
      #pragma unroll
      for (int r = 0; r < 4; r++) {
        float vv = (acc[mf][nf][r] + bv[nf]) * scale;
        size_t idx = (size_t)(m0 + wr * 64 + mf * 16 + g * 4 + r) * 1024
                   + n0 + wc * 64 + nf * 16 + ln;
        if constexpr (OUT_IS_F32) ((float*)Cv)[idx] = vv;
        else                      ((short*)Cv)[idx] = f2bf(vv);
      }
}

// ---------------------------------------------------------------------------
// Flash attention v12 (round-12 verified): swapped QK^T, in-register softmax,
// butterfly P-routing, l via MFMA against ones, tree row-max.
// ---------------------------------------------------------------------------
__global__ __launch_bounds__(256, 2) void flash_attn(
    const short* __restrict__ Q, const short* __restrict__ Kswz,
    const short* __restrict__ Vt, short* __restrict__ CTX)
{
  __shared__ short Klds[2][64 * 64];
  __shared__ short Vlds[2][64 * 64];

  const int t  = threadIdx.x;
  const int w  = t >> 6, l = t & 63, g = l >> 4, ln = l & 15;
  const int rb0 = g & 1, rb1 = g >> 1;            // route bits
  const bool sendK = (rb0 ^ rb1) != 0;
  const int bh   = blockIdx.x & 127;               // XCD-local remap
  const int tile = blockIdx.x >> 7;
  const int b = bh >> 4, h = bh & 15;
  const size_t rowbase = (size_t)b * SEQ;
  const int colbase = h * HD;
  const int q0w = tile * 128 + w * 32;

  const short* Kg = Kswz + rowbase * 1024 + colbase;
  const short* Vg = Vt + (size_t)bh * 65536;
  const int c0 = w * 64 + l;

  const short one_bf = (short)0x3F80;              // bf16 1.0
  const s16x8 ones = { one_bf, one_bf, one_bf, one_bf,
                       one_bf, one_bf, one_bf, one_bf };

  s16x8 qf[2][2];
  #pragma unroll
  for (int mf = 0; mf < 2; mf++)
    #pragma unroll
    for (int kf = 0; kf < 2; kf++)
      qf[mf][kf] = *(const s16x8*)(Q + (rowbase + q0w + mf * 16 + ln) * 1024
                                     + colbase + kf * 32 + g * 8);

  f32x4 acc_o[2][4];
  f32x4 l_acc[2];
  #pragma unroll
  for (int i = 0; i < 2; i++) {
    l_acc[i] = (f32x4)0.0f;
    #pragma unroll
    for (int j = 0; j < 4; j++) acc_o[i][j] = (f32x4)0.0f;
  }

  float m_run[2] = { -1e30f, -1e30f };

  auto STAGE = [&](int buf, int nt) {
    #pragma unroll
    for (int i = 0; i < 2; i++) {
      int c = c0 + i * 256;
      gl_lds16(Kg + (size_t)(nt * 64 + (c >> 3)) * 1024 + (c & 7) * 8,
               &Klds[buf][(i * 256 + w * 64) * 8]);
      gl_lds16(Vg + (size_t)(c >> 3) * 1024 + nt * 64 + (c & 7) * 8,
               &Vlds[buf][(i * 256 + w * 64) * 8]);
    }
  };

  STAGE(0, 0);
  __syncthreads();

  int cur = 0;
  for (int kt = 0; kt < 16; kt++) {
    if (kt < 15) STAGE(cur ^ 1, kt + 1);

    const short* Kc = &Klds[cur][0];
    const short* Vc = &Vlds[cur][0];

    // ---- QK^T swapped: sT[kk4][kq]; lane: q=kq*16+ln, k=kk4*16+4g+r ----
    f32x4 sT[4][2];
    #pragma unroll
    for (int i = 0; i < 4; i++)
      #pragma unroll
      for (int j = 0; j < 2; j++) sT[i][j] = (f32x4)0.0f;

    __builtin_amdgcn_s_setprio(1);
    #pragma unroll
    for (int kf = 0; kf < 2; kf++) {
      s16x8 kfr[4];
      #pragma unroll
      for (int nf = 0; nf < 4; nf++)
        kfr[nf] = *(const s16x8*)(Kc + (nf * 16 + ln) * 64
                                     + (((kf * 4 + g) ^ (ln & 7)) * 8));
      #pragma unroll
      for (int kk4 = 0; kk4 < 4; kk4++)
        #pragma unroll
        for (int kq = 0; kq < 2; kq++)
          sT[kk4][kq] = __builtin_amdgcn_mfma_f32_16x16x32_bf16(
              asbf(kfr[kk4]), asbf(qf[kq][kf]), sT[kk4][kq], 0, 0, 0);
    }
    __builtin_amdgcn_s_setprio(0);

    // ---- row max: balanced tree (depth 4) + 2 shfl over g-groups ----
    float rm[2];
    #pragma unroll
    for (int kq = 0; kq < 2; kq++) {
      float a0 = fmaxf(sT[0][kq][0], sT[0][kq][1]);
      float a1 = fmaxf(sT[0][kq][2], sT[0][kq][3]);
      float a2 = fmaxf(sT[1][kq][0], sT[1][kq][1]);
      float a3 = fmaxf(sT[1][kq][2], sT[1][kq][3]);
      float a4 = fmaxf(sT[2][kq][0], sT[2][kq][1]);
      float a5 = fmaxf(sT[2][kq][2], sT[2][kq][3]);
      float a6 = fmaxf(sT[3][kq][0], sT[3][kq][1]);
      float a7 = fmaxf(sT[3][kq][2], sT[3][kq][3]);
      float b0 = fmaxf(a0, a1), b1 = fmaxf(a2, a3);
      float b2 = fmaxf(a4, a5), b3 = fmaxf(a6, a7);
      float mx = fmaxf(fmaxf(b0, b1), fmaxf(b2, b3));
      mx = fmaxf(mx, __shfl_xor(mx, 16));
      mx = fmaxf(mx, __shfl_xor(mx, 32));
      rm[kq] = mx;
    }
    float worst = fmaxf(rm[0] - m_run[0], rm[1] - m_run[1]);

    if (__all(worst <= 8.0f)) {
      #pragma unroll
      for (int kq = 0; kq < 2; kq++) {
        float m0v = m_run[kq];
        #pragma unroll
        for (int kk4 = 0; kk4 < 4; kk4++)
          #pragma unroll
          for (int r = 0; r < 4; r++)
            sT[kk4][kq][r] = exp2f(sT[kk4][kq][r] - m0v);
      }
    } else {
      float sc[2];
      #pragma unroll
      for (int kq = 0; kq < 2; kq++) {
        float mnew = fmaxf(m_run[kq], rm[kq]);
        sc[kq] = exp2f(m_run[kq] - mnew);
        m_run[kq] = mnew;
        #pragma unroll
        for (int kk4 = 0; kk4 < 4; kk4++)
          #pragma unroll
          for (int r = 0; r < 4; r++)
            sT[kk4][kq][r] = exp2f(sT[kk4][kq][r] - mnew);
      }
      // rescale acc_o and l_acc: sc for q = mf*16 + g*4 + r at lane (g*4+r)
      #pragma unroll
      for (int mf = 0; mf < 2; mf++)
        #pragma unroll
        for (int r = 0; r < 4; r++) {
          float scr = __shfl(sc[mf], g * 4 + r);
          l_acc[mf][r] *= scr;
          #pragma unroll
          for (int nf = 0; nf < 4; nf++) acc_o[mf][nf][r] *= scr;
        }
    }

    // ---- pack P to bf16 dword pairs: D[kk4][kq][di] ----
    uint32_t D[4][2][2];
    #pragma unroll
    for (int kk4 = 0; kk4 < 4; kk4++)
      #pragma unroll
      for (int kq = 0; kq < 2; kq++) {
        asm("v_cvt_pk_bf16_f32 %0, %1, %2"
            : "=v"(D[kk4][kq][0]) : "v"(sT[kk4][kq][0]), "v"(sT[kk4][kq][1]));
        asm("v_cvt_pk_bf16_f32 %0, %1, %2"
            : "=v"(D[kk4][kq][1]) : "v"(sT[kk4][kq][2]), "v"(sT[kk4][kq][3]));
      }

    // ---- 2-stage butterfly route -> pa[kq][kp] (PV A-frags) ----
    s16x8 pa[2][2];
    #pragma unroll
    for (int kq = 0; kq < 2; kq++)
      #pragma unroll
      for (int kp = 0; kp < 2; kp++) {
        uint32_t K0 = rb1 ? D[2*kp+1][kq][0] : D[2*kp][kq][0];
        uint32_t K1 = rb1 ? D[2*kp+1][kq][1] : D[2*kp][kq][1];
        uint32_t S0 = rb1 ? D[2*kp][kq][0]   : D[2*kp+1][kq][0];
        uint32_t S1 = rb1 ? D[2*kp][kq][1]   : D[2*kp+1][kq][1];
        uint32_t R0 = (uint32_t)__shfl_xor((int)S0, 32);
        uint32_t R1 = (uint32_t)__shfl_xor((int)S1, 32);
        uint32_t T0 = sendK ? K0 : R0, T1 = sendK ? K1 : R1;
        uint32_t V0 = sendK ? R0 : K0, V1 = sendK ? R1 : K1;
        uint32_t U0 = (uint32_t)__shfl_xor((int)T0, 16);
        uint32_t U1 = (uint32_t)__shfl_xor((int)T1, 16);
        u32x4 dw = { rb0 ? U0 : V0, rb0 ? U1 : V1,
                     rb0 ? V0 : U0, rb0 ? V1 : U1 };
        pa[kq][kp] = __builtin_bit_cast(s16x8, dw);
      }

    // ---- PV (+ l via MFMA against ones) ----
    s16x8 vbf[4][2];
    #pragma unroll
    for (int nf = 0; nf < 4; nf++)
      #pragma unroll
      for (int kf = 0; kf < 2; kf++)
        vbf[nf][kf] = *(const s16x8*)(Vc + (nf * 16 + ln) * 64
                                         + (((kf * 4 + g) ^ (ln & 7)) * 8));

    __builtin_amdgcn_s_setprio(1);
    #pragma unroll
    for (int kf = 0; kf < 2; kf++)
      #pragma unroll
      for (int mf = 0; mf < 2; mf++) {
        l_acc[mf] = __builtin_amdgcn_mfma_f32_16x16x32_bf16(
            asbf(pa[mf][kf]), asbf(ones), l_acc[mf], 0, 0, 0);
        #pragma unroll
        for (int nf = 0; nf < 4; nf++)
          acc_o[mf][nf] = __builtin_amdgcn_mfma_f32_16x16x32_bf16(
              asbf(pa[mf][kf]), asbf(vbf[nf][kf]), acc_o[mf][nf], 0, 0, 0);
      }
    __builtin_amdgcn_s_setprio(0);

    __syncthreads();
    cur ^= 1;
  }

  // ---- finalize: l_acc rows match acc_o rows -> lane-local divide ----
  #pragma unroll
  for (int mf = 0; mf < 2; mf++)
    #pragma unroll
    for (int r = 0; r < 4; r++) {
      float inv = 1.0f / l_acc[mf][r];
      size_t row = rowbase + q0w + mf * 16 + g * 4 + r;
      #pragma unroll
      for (int nf = 0; nf < 4; nf++)
        CTX[row * 1024 + colbase + nf * 16 + ln] = f2bf(acc_o[mf][nf][r] * inv);
    }
}

// ---------------------------------------------------------------------------
// Fallback flash (round-6 proven version): reg-staged K/V, plain layouts.
// ---------------------------------------------------------------------------
__global__ __launch_bounds__(256, 2) void flash_attn_fb(
    const short* __restrict__ Q, const short* __restrict__ K,
    const short* __restrict__ V, short* __restrict__ CTX)
{
  __shared__ short Klds[2][64 * 64];
  __shared__ short Vtl [2][64 * 64];
  __shared__ short Plds[4][32 * 72];

  const int t  = threadIdx.x;
  const int w  = t >> 6, l = t & 63, g = l >> 4, ln = l & 15;
  const int tile = blockIdx.x & 7;
  const int bh   = blockIdx.x >> 3;
  const int b = bh >> 4, h = bh & 15;
  const size_t rowbase = (size_t)b * SEQ;
  const int colbase = h * HD;
  const int q0w = tile * 128 + w * 32;

  const int kk0  = t >> 3;
  const int dblk = t & 7;
  const int ksw  = (dblk ^ (kk0 & 7)) * 8;
  const int kWr  = kk0 * 64 + dblk * 8;
  const short* Kg = K + rowbase * 1024 + colbase + ksw;
  const short* Vg = V + rowbase * 1024 + colbase + dblk * 8;

  s16x8 qf[2][2];
  #pragma unroll
  for (int mf = 0; mf < 2; mf++)
    #pragma unroll
    for (int kf = 0; kf < 2; kf++)
      qf[mf][kf] = *(const s16x8*)(Q + (rowbase + q0w + mf * 16 + ln) * 1024
                                     + colbase + kf * 32 + g * 8);

  f32x4 acc_o[2][4];
  #pragma unroll
  for (int i = 0; i < 2; i++)
    #pragma unroll
    for (int j = 0; j < 4; j++) acc_o[i][j] = (f32x4)0.0f;

  float m_run[2][4], l_run[2][4];
  #pragma unroll
  for (int i = 0; i < 2; i++)
    #pragma unroll
    for (int r = 0; r < 4; r++) { m_run[i][r] = -1e30f; l_run[i][r] = 0.0f; }

  auto storeKV = [&](int buf, s16x8 ka, s16x8 kb, s16x8 va, s16x8 vb8) {
    short* Kd = &Klds[buf][0];
    short* Vd = &Vtl[buf][0];
    *(s16x8*)(Kd + kWr)        = ka;
    *(s16x8*)(Kd + kWr + 2048) = kb;
    #pragma unroll
    for (int e = 0; e < 8; e++) {
      int a0 = (dblk * 8 + e) * 64 + (kk0 ^ ((e ^ dblk) * 8));
      Vd[a0]      = va[e];
      Vd[a0 ^ 32] = vb8[e];
    }
  };

  s16x8 kvA = *(const s16x8*)(Kg + (size_t)kk0 * 1024);
  s16x8 kvB = *(const s16x8*)(Kg + (size_t)(kk0 + 32) * 1024);
  s16x8 vvA = *(const s16x8*)(Vg + (size_t)kk0 * 1024);
  s16x8 vvB = *(const s16x8*)(Vg + (size_t)(kk0 + 32) * 1024);
  storeKV(0, kvA, kvB, vvA, vvB);

  int cur = 0;
  for (int kt = 0; kt < 16; kt++) {
    if (kt < 15) {
      const size_t r0 = (size_t)((kt + 1) * 64 + kk0) * 1024;
      kvA = *(const s16x8*)(Kg + r0);
      kvB = *(const s16x8*)(Kg + r0 + 32 * 1024);
      vvA = *(const s16x8*)(Vg + r0);
      vvB = *(const s16x8*)(Vg + r0 + 32 * 1024);
    }
    __syncthreads();

    const short* Kc = &Klds[cur][0];
    const short* Vc = &Vtl[cur][0];

    f32x4 s_acc[2][4];
    #pragma unroll
    for (int i = 0; i < 2; i++)
      #pragma unroll
      for (int j = 0; j < 4; j++) s_acc[i][j] = (f32x4)0.0f;

    #pragma unroll
    for (int kf = 0; kf < 2; kf++) {
      s16x8 kfr[4];
      #pragma unroll
      for (int nf = 0; nf < 4; nf++)
        kfr[nf] = *(const s16x8*)(Kc + (nf * 16 + ln) * 64
                                     + (((kf * 4 + g) ^ (ln & 7)) * 8));
      #pragma unroll
      for (int mf = 0; mf < 2; mf++)
        #pragma unroll
        for (int nf = 0; nf < 4; nf++)
          s_acc[mf][nf] = __builtin_amdgcn_mfma_f32_16x16x32_bf16(
              asbf(qf[mf][kf]), asbf(kfr[nf]), s_acc[mf][nf], 0, 0, 0);
    }

    float smax[2][4];
    float worst = -1e30f;
    #pragma unroll
    for (int mf = 0; mf < 2; mf++)
      #pragma unroll
      for (int r = 0; r < 4; r++) {
        float mx = fmaxf(fmaxf(s_acc[mf][0][r], s_acc[mf][1][r]),
                         fmaxf(s_acc[mf][2][r], s_acc[mf][3][r]));
        mx = dpp_fmax16(mx);
        smax[mf][r] = mx;
        worst = fmaxf(worst, mx - m_run[mf][r]);
      }

    if (__all(worst <= 8.0f)) {
      #pragma unroll
      for (int mf = 0; mf < 2; mf++)
        #pragma unroll
        for (int r = 0; r < 4; r++) {
          float m0v = m_run[mf][r];
          float rs = 0.0f;
          #pragma unroll
          for (int nf = 0; nf < 4; nf++) {
            float pv = exp2f(s_acc[mf][nf][r] - m0v);
            s_acc[mf][nf][r] = pv;
            rs += pv;
          }
          l_run[mf][r] += rs;
        }
    } else {
      #pragma unroll
      for (int mf = 0; mf < 2; mf++)
        #pragma unroll
        for (int r = 0; r < 4; r++) {
          float mnew = fmaxf(m_run[mf][r], smax[mf][r]);
          float sc = exp2f(m_run[mf][r] - mnew);
          m_run[mf][r] = mnew;
          float rs = 0.0f;
          #pragma unroll
          for (int nf = 0; nf < 4; nf++) {
            float pv = exp2f(s_acc[mf][nf][r] - mnew);
            s_acc[mf][nf][r] = pv;
            rs += pv;
          }
          l_run[mf][r] = l_run[mf][r] * sc + rs;
          #pragma unroll
          for (int nf = 0; nf < 4; nf++) acc_o[mf][nf][r] *= sc;
        }
    }

    short* Pw = &Plds[w][0];
    #pragma unroll
    for (int mf = 0; mf < 2; mf++)
      #pragma unroll
      for (int nf = 0; nf < 4; nf++) {
        uint32_t p01, p23;
        asm("v_cvt_pk_bf16_f32 %0, %1, %2"
            : "=v"(p01) : "v"(s_acc[mf][nf][0]), "v"(s_acc[mf][nf][1]));
        asm("v_cvt_pk_bf16_f32 %0, %1, %2"
            : "=v"(p23) : "v"(s_acc[mf][nf][2]), "v"(s_acc[mf][nf][3]));
        int pb = (mf * 16 + g * 4) * 72 + ((nf * 16 + ln) ^ (g << 3));
        Pw[pb]       = (short)p01;
        Pw[pb + 72]  = (short)(p01 >> 16);
        Pw[pb + 144] = (short)p23;
        Pw[pb + 216] = (short)(p23 >> 16);
      }

    s16x8 pa[2][2], vbf[4][2];
    #pragma unroll
    for (int mf = 0; mf < 2; mf++)
      #pragma unroll
      for (int kf = 0; kf < 2; kf++)
        pa[mf][kf] = *(const s16x8*)(
            &Pw[(mf * 16 + ln) * 72 + (((kf * 4 + g) ^ (ln >> 2)) << 3)]);
    #pragma unroll
    for (int nf = 0; nf < 4; nf++)
      #pragma unroll
      for (int kf = 0; kf < 2; kf++) {
        int d  = nf * 16 + ln;
        int sw = (d & 7) ^ (d >> 3);
        vbf[nf][kf] = *(const s16x8*)(Vc + d * 64 + ((kf * 32 + g * 8) ^ (sw * 8)));
      }

    #pragma unroll
    for (int kf = 0; kf < 2; kf++)
      #pragma unroll
      for (int mf = 0; mf < 2; mf++)
        #pragma unroll
        for (int nf = 0; nf < 4; nf++)
          acc_o[mf][nf] = __builtin_amdgcn_mfma_f32_16x16x32_bf16(
              asbf(pa[mf][kf]), asbf(vbf[nf][kf]), acc_o[mf][nf], 0, 0, 0);

    if (kt < 15) {
      storeKV(cur ^ 1, kvA, kvB, vvA, vvB);
      cur ^= 1;
    }
  }

  #pragma unroll
  for (int mf = 0; mf < 2; mf++)
    #pragma unroll
    for (int r = 0; r < 4; r++) {
      float inv = 1.0f / dpp_fadd16(l_run[mf][r]);
      size_t row = rowbase + q0w + mf * 16 + g * 4 + r;
      #pragma unroll
      for (int nf = 0; nf < 4; nf++)
        CTX[row * 1024 + colbase + nf * 16 + ln] = f2bf(acc_o[mf][nf][r] * inv);
    }
}

// ---------------------------------------------------------------------------
extern "C" void kernel_launch(void* const* d_in, const int* in_sizes, int n_in,
                              void* d_out, int out_size, void* d_ws, size_t ws_size,
                              hipStream_t stream) {
  const float* query = (const float*)d_in[0];
  const float* key   = (const float*)d_in[1];
  const float* value = (const float*)d_in[2];
  const float* Wq = (const float*)d_in[3];
  const float* bq = (const float*)d_in[4];
  const float* Wk = (const float*)d_in[5];
  const float* bk = (const float*)d_in[6];
  const float* Wv = (const float*)d_in[7];
  const float* bv = (const float*)d_in[8];
  const float* Wo = (const float*)d_in[9];
  const float* bo = (const float*)d_in[10];

  const size_t E = (size_t)MTOT * 1024;
  short* Qb = (short*)d_ws;
  short* Kb = Qb + E;     // holds col-swizzled K (fast path)
  short* Vb = Kb + E;
  short* Cx = Vb + E;
  short* T  = Cx + E;     // cvt ping-pong; reused as V-transposed for flash
  short* Wb = T  + E;

  const size_t need = (5 * E + 4ull * 1048576) * 2;   // ~92.3 MB
  dim3 gg(MTOT / 128, HIDDEN / 128), bb(256), bb512(512);
  dim3 fg(BATCH * HEADS * (SEQ / 128));

  if (ws_size >= need) {
    cvt_w<<<dim3(512, 4), bb, 0, stream>>>(Wq, Wk, Wv, Wo, Wb);
    cvt_x<<<4096, bb, 0, stream>>>(query, T);
    gemm_bf16_dma<1><<<gg, bb512, 0, stream>>>(T, Wb + 0 * 1048576, bq, Qb, QSCALE);
    cvt_x<<<4096, bb, 0, stream>>>(key, T);
    gemm_bf16_dma<2><<<gg, bb512, 0, stream>>>(T, Wb + 1 * 1048576, bk, Kb, 1.0f);
    cvt_x<<<4096, bb, 0, stream>>>(value, T);
    gemm_bf16_dma<1><<<gg, bb512, 0, stream>>>(T, Wb + 2 * 1048576, bv, Vb, 1.0f);
    vtrans<<<dim3(16, 16, 8), bb, 0, stream>>>(Vb, T);
    flash_attn<<<fg, bb, 0, stream>>>(Qb, Kb, T, Cx);
    gemm_bf16_dma<0><<<gg, bb512, 0, stream>>>(Cx, Wb + 3 * 1048576, bo, (float*)d_out, 1.0f);
  } else {
    gemm_bt_bias<false, false><<<gg, bb, 0, stream>>>(query, Wq, bq, Qb, QSCALE);
    gemm_bt_bias<false, false><<<gg, bb, 0, stream>>>(key,   Wk, bk, Kb, 1.0f);
    gemm_bt_bias<false, false><<<gg, bb, 0, stream>>>(value, Wv, bv, Vb, 1.0f);
    flash_attn_fb<<<fg, bb, 0, stream>>>(Qb, Kb, Vb, Cx);
    gemm_bt_bias<true, true><<<gg, bb, 0, stream>>>(Cx, Wo, bo, (float*)d_out, 1.0f);
  }
}

// Round 14
// 212.528 us; speedup vs baseline: 1.0545x; 1.0545x over previous
//
#include <hip/hip_runtime.h>
#include <hip/hip_bf16.h>
#include <stdint.h>

#define HIDDEN 1024
#define HEADS 16
#define HD 64
#define BATCH 8
#define SEQ 1024
#define MTOT (BATCH*SEQ)   // 8192 rows total

typedef __attribute__((ext_vector_type(4))) float  f32x4;
typedef __attribute__((ext_vector_type(4))) float  float4v;
typedef __attribute__((ext_vector_type(8))) short  s16x8;
typedef __attribute__((ext_vector_type(4))) short  s16x4;
typedef __attribute__((ext_vector_type(4))) unsigned int u32x4;
typedef __bf16 bf16x8 __attribute__((ext_vector_type(8)));

// log2(e) / sqrt(HEAD_DIM)
#define QSCALE 0.18033688011112042f

__device__ __forceinline__ short f2bf(float f) {
  uint32_t u = __builtin_bit_cast(uint32_t, f);
  u += 0x7FFFu + ((u >> 16) & 1u);          // RNE to bf16
  return (short)(u >> 16);
}
__device__ __forceinline__ bf16x8 asbf(s16x8 v) {
  return __builtin_bit_cast(bf16x8, v);
}

// ---- DPP 16-lane reductions (VALU only) -----------------------------------
__device__ __forceinline__ float dpp_fmax16(float x) {
  int t;
  t = __builtin_amdgcn_update_dpp(0, __builtin_bit_cast(int, x), 0xB1, 0xF, 0xF, true);
  x = fmaxf(x, __builtin_bit_cast(float, t));
  t = __builtin_amdgcn_update_dpp(0, __builtin_bit_cast(int, x), 0x4E, 0xF, 0xF, true);
  x = fmaxf(x, __builtin_bit_cast(float, t));
  t = __builtin_amdgcn_update_dpp(0, __builtin_bit_cast(int, x), 0x141, 0xF, 0xF, true);
  x = fmaxf(x, __builtin_bit_cast(float, t));
  t = __builtin_amdgcn_update_dpp(0, __builtin_bit_cast(int, x), 0x140, 0xF, 0xF, true);
  x = fmaxf(x, __builtin_bit_cast(float, t));
  return x;
}
__device__ __forceinline__ float dpp_fadd16(float x) {
  int t;
  t = __builtin_amdgcn_update_dpp(0, __builtin_bit_cast(int, x), 0xB1, 0xF, 0xF, true);
  x += __builtin_bit_cast(float, t);
  t = __builtin_amdgcn_update_dpp(0, __builtin_bit_cast(int, x), 0x4E, 0xF, 0xF, true);
  x += __builtin_bit_cast(float, t);
  t = __builtin_amdgcn_update_dpp(0, __builtin_bit_cast(int, x), 0x141, 0xF, 0xF, true);
  x += __builtin_bit_cast(float, t);
  t = __builtin_amdgcn_update_dpp(0, __builtin_bit_cast(int, x), 0x140, 0xF, 0xF, true);
  x += __builtin_bit_cast(float, t);
  return x;
}

// global -> LDS direct DMA, 16 B per lane.
typedef const __attribute__((address_space(1))) void* gvp;
typedef __attribute__((address_space(3)))       void* lvp;
__device__ __forceinline__ void gl_lds16(const void* g, const void* ldsbase) {
  __builtin_amdgcn_global_load_lds((gvp)(uintptr_t)g,
                                   (lvp)(uintptr_t)(uint32_t)(uintptr_t)ldsbase,
                                   16, 0, 0);
}

// ---------------------------------------------------------------------------
// fp32 -> bf16 converters
// ---------------------------------------------------------------------------
__global__ __launch_bounds__(256) void cvt_x(const float* __restrict__ src,
                                             short* __restrict__ dst) {
  int i = blockIdx.x * 256 + threadIdx.x;
  float4v a = *(const float4v*)(src + (size_t)i * 8);
  float4v b = *(const float4v*)(src + (size_t)i * 8 + 4);
  s16x8 o = { f2bf(a.x), f2bf(a.y), f2bf(a.z), f2bf(a.w),
              f2bf(b.x), f2bf(b.y), f2bf(b.z), f2bf(b.w) };
  *(s16x8*)(dst + (size_t)i * 8) = o;
}

// batched: z = 0/1/2 -> query/key/value, dst = T + z*E
__global__ __launch_bounds__(256) void cvt_x3(const float* __restrict__ s0,
                                              const float* __restrict__ s1,
                                              const float* __restrict__ s2,
                                              short* __restrict__ dst) {
  int z = blockIdx.y;
  const float* src = (z == 0) ? s0 : (z == 1) ? s1 : s2;
  int i = blockIdx.x * 256 + threadIdx.x;
  float4v a = *(const float4v*)(src + (size_t)i * 8);
  float4v b = *(const float4v*)(src + (size_t)i * 8 + 4);
  s16x8 o = { f2bf(a.x), f2bf(a.y), f2bf(a.z), f2bf(a.w),
              f2bf(b.x), f2bf(b.y), f2bf(b.z), f2bf(b.w) };
  *(s16x8*)(dst + (size_t)z * ((size_t)MTOT * 1024) + (size_t)i * 8) = o;
}

__global__ __launch_bounds__(256) void cvt_w(const float* __restrict__ s0,
                                             const float* __restrict__ s1,
                                             const float* __restrict__ s2,
                                             const float* __restrict__ s3,
                                             short* __restrict__ dst) {
  int z = blockIdx.y;
  const float* src = (z == 0) ? s0 : (z == 1) ? s1 : (z == 2) ? s2 : s3;
  int i = blockIdx.x * 256 + threadIdx.x;
  float4v a = *(const float4v*)(src + (size_t)i * 8);
  float4v b = *(const float4v*)(src + (size_t)i * 8 + 4);
  s16x8 o = { f2bf(a.x), f2bf(a.y), f2bf(a.z), f2bf(a.w),
              f2bf(b.x), f2bf(b.y), f2bf(b.z), f2bf(b.w) };
  *(s16x8*)(dst + (size_t)z * 1048576 + (size_t)i * 8) = o;
}

// ---------------------------------------------------------------------------
// V transpose: Vb[s][h*64+d] -> Vt[(b*16+h)*64+d][s], with flash's k-block
// swizzle (block ^= d&7) pre-applied per 64-k tile. Coalesced both sides.
// ---------------------------------------------------------------------------
__global__ __launch_bounds__(256) void vtrans(const short* __restrict__ Vb,
                                              short* __restrict__ Vt) {
  __shared__ short lt[64 * 64];
  const int t = threadIdx.x;
  const int kt0 = blockIdx.x, h = blockIdx.y, b = blockIdx.z;
  const short* src = Vb + ((size_t)(b * 1024 + kt0 * 64)) * 1024 + h * 64;

  #pragma unroll
  for (int i = 0; i < 2; i++) {
    int c = t + i * 256;
    int s = c >> 3, dc = c & 7;
    s16x8 v = *(const s16x8*)(src + (size_t)s * 1024 + dc * 8);
    int dcp = dc ^ (s & 7) ^ ((s >> 3) & 7);
    *(s16x8*)(&lt[s * 64 + dcp * 8]) = v;
  }
  __syncthreads();

  short* dst = Vt + ((size_t)(b * 16 + h) * 64) * 1024 + kt0 * 64;
  #pragma unroll
  for (int i = 0; i < 2; i++) {
    int c = t + i * 256;
    int d = c >> 3, kc = c & 7;
    s16x8 o;
    #pragma unroll
    for (int j = 0; j < 8; j++) {
      int s = kc * 8 + j;
      o[j] = lt[s * 64 + (((d >> 3) ^ j ^ kc) * 8) + (d & 7)];
    }
    *(s16x8*)(dst + (size_t)d * 1024 + (kc ^ (d & 7)) * 8) = o;
  }
}

// ---------------------------------------------------------------------------
// GEMM core (r12-proven 4-wave 256-thr, 128x128, BK=32, DMA staging).
// Template CMODE: 0 = f32 out, 1 = bf16 out, 2 = bf16 out + K-col swizzle.
// ---------------------------------------------------------------------------
template<int CMODE>
__global__ __launch_bounds__(256, 2) void gemm_bf16_dma(
    const short* __restrict__ A, const short* __restrict__ Wb,
    const float* __restrict__ bias, void* __restrict__ Cv, float scale)
{
  __shared__ short Alds[128 * 32];
  __shared__ short Blds[128 * 32];

  const int t  = threadIdx.x;
  const int w  = t >> 6, l = t & 63, g = l >> 4, ln = l & 15;
  const int wr = w >> 1, wc = w & 1;
  const int m0 = blockIdx.x * 128, n0 = blockIdx.y * 128;

  f32x4 acc[4][4];
  #pragma unroll
  for (int i = 0; i < 4; i++)
    #pragma unroll
    for (int j = 0; j < 4; j++) acc[i][j] = (f32x4)0.0f;

  for (int k0 = 0; k0 < 1024; k0 += 32) {
    #pragma unroll
    for (int i = 0; i < 2; i++) {
      int c = i * 256 + w * 64 + l;
      int row = c >> 2, col8 = c & 3;
      gl_lds16(A  + (size_t)(m0 + row) * 1024 + k0 + col8 * 8,
               &Alds[(i * 256 + w * 64) * 8]);
      gl_lds16(Wb + (size_t)(n0 + row) * 1024 + k0 + col8 * 8,
               &Blds[(i * 256 + w * 64) * 8]);
    }
    __syncthreads();

    s16x8 af[4], bfr[4];
    #pragma unroll
    for (int mf = 0; mf < 4; mf++)
      af[mf] = *(const s16x8*)(&Alds[(wr * 64 + mf * 16 + ln) * 32 + g * 8]);
    #pragma unroll
    for (int nf = 0; nf < 4; nf++)
      bfr[nf] = *(const s16x8*)(&Blds[(wc * 64 + nf * 16 + ln) * 32 + g * 8]);

    __builtin_amdgcn_s_setprio(1);
    #pragma unroll
    for (int mf = 0; mf < 4; mf++)
      #pragma unroll
      for (int nf = 0; nf < 4; nf++)
        acc[mf][nf] = __builtin_amdgcn_mfma_f32_16x16x32_bf16(
            asbf(af[mf]), asbf(bfr[nf]), acc[mf][nf], 0, 0, 0);
    __builtin_amdgcn_s_setprio(0);
    __syncthreads();
  }

  float bv[4];
  #pragma unroll
  for (int nf = 0; nf < 4; nf++) bv[nf] = bias[n0 + wc * 64 + nf * 16 + ln];
  #pragma unroll
  for (int mf = 0; mf < 4; mf++)
    #pragma unroll
    for (int nf = 0; nf < 4; nf++)
      #pragma unroll
      for (int r = 0; r < 4; r++) {
        float vv = (acc[mf][nf][r] + bv[nf]) * scale;
        size_t idx = (size_t)(m0 + wr * 64 + mf * 16 + g * 4 + r) * 1024
                   + n0 + wc * 64 + nf * 16 + ln;
        if constexpr (CMODE == 0) ((float*)Cv)[idx] = vv;
        else if constexpr (CMODE == 1) ((short*)Cv)[idx] = f2bf(vv);
        else {
          size_t idxs = idx ^ (size_t)(((g * 4 + r) & 7) * 8);  // col^8*(row&7)
          ((short*)Cv)[idxs] = f2bf(vv);
        }
      }
}

// ---------------------------------------------------------------------------
// z-batched Q/K/V projection GEMM: one dispatch, grid.z = 0/1/2 selects
// input slice of X3 (3 contiguous bf16 matrices), weight slice, bias, dest.
// z==1 (K) applies the flash K-col swizzle; z==0 (Q) applies QSCALE.
// Body identical to gemm_bf16_dma (proven).
// ---------------------------------------------------------------------------
__global__ __launch_bounds__(256, 2) void gemm_qkv(
    const short* __restrict__ X3, const short* __restrict__ Wb,
    const float* __restrict__ bq, const float* __restrict__ bk,
    const float* __restrict__ bv_, short* __restrict__ Qb,
    short* __restrict__ Kb, short* __restrict__ Vb)
{
  __shared__ short Alds[128 * 32];
  __shared__ short Blds[128 * 32];

  const size_t E = (size_t)MTOT * 1024;
  const int z = blockIdx.z;
  const short* A  = X3 + (size_t)z * E;
  const short* W  = Wb + (size_t)z * 1048576;
  const float* bias = (z == 0) ? bq : (z == 1) ? bk : bv_;
  short* Cv = (z == 0) ? Qb : (z == 1) ? Kb : Vb;
  const float scale = (z == 0) ? QSCALE : 1.0f;
  const bool kswz = (z == 1);

  const int t  = threadIdx.x;
  const int w  = t >> 6, l = t & 63, g = l >> 4, ln = l & 15;
  const int wr = w >> 1, wc = w & 1;
  const int m0 = blockIdx.x * 128, n0 = blockIdx.y * 128;

  f32x4 acc[4][4];
  #pragma unroll
  for (int i = 0; i < 4; i++)
    #pragma unroll
    for (int j = 0; j < 4; j++) acc[i][j] = (f32x4)0.0f;

  for (int k0 = 0; k0 < 1024; k0 += 32) {
    #pragma unroll
    for (int i = 0; i < 2; i++) {
      int c = i * 256 + w * 64 + l;
      int row = c >> 2, col8 = c & 3;
      gl_lds16(A + (size_t)(m0 + row) * 1024 + k0 + col8 * 8,
               &Alds[(i * 256 + w * 64) * 8]);
      gl_lds16(W + (size_t)(n0 + row) * 1024 + k0 + col8 * 8,
               &Blds[(i * 256 + w * 64) * 8]);
    }
    __syncthreads();

    s16x8 af[4], bfr[4];
    #pragma unroll
    for (int mf = 0; mf < 4; mf++)
      af[mf] = *(const s16x8*)(&Alds[(wr * 64 + mf * 16 + ln) * 32 + g * 8]);
    #pragma unroll
    for (int nf = 0; nf < 4; nf++)
      bfr[nf] = *(const s16x8*)(&Blds[(wc * 64 + nf * 16 + ln) * 32 + g * 8]);

    __builtin_amdgcn_s_setprio(1);
    #pragma unroll
    for (int mf = 0; mf < 4; mf++)
      #pragma unroll
      for (int nf = 0; nf < 4; nf++)
        acc[mf][nf] = __builtin_amdgcn_mfma_f32_16x16x32_bf16(
            asbf(af[mf]), asbf(bfr[nf]), acc[mf][nf], 0, 0, 0);
    __builtin_amdgcn_s_setprio(0);
    __syncthreads();
  }

  float bv[4];
  #pragma unroll
  for (int nf = 0; nf < 4; nf++) bv[nf] = bias[n0 + wc * 64 + nf * 16 + ln];
  #pragma unroll
  for (int mf = 0; mf < 4; mf++)
    #pragma unroll
    for (int nf = 0; nf < 4; nf++)
      #pragma unroll
      for (int r = 0; r < 4; r++) {
        float vv = (acc[mf][nf][r] + bv[nf]) * scale;
        size_t idx = (size_t)(m0 + wr * 64 + mf * 16 + g * 4 + r) * 1024
                   + n0 + wc * 64 + nf * 16 + ln;
        if (kswz) idx ^= (size_t)(((g * 4 + r) & 7) * 8);
        Cv[idx] = f2bf(vv);
      }
}

// ---------------------------------------------------------------------------
// Fallback GEMM (reg-staged conversion), C = (A @ W^T + bias) * scale
// ---------------------------------------------------------------------------
template<bool A_IS_BF16, bool OUT_IS_F32>
__global__ __launch_bounds__(256, 2) void gemm_bt_bias(
    const void* __restrict__ Av, const float* __restrict__ W,
    const float* __restrict__ bias, void* __restrict__ Cv, float scale)
{
  __shared__ short Alds[128 * 32];
  __shared__ short Blds[128 * 32];

  const int t  = threadIdx.x;
  const int w  = t >> 6, l = t & 63, g = l >> 4, ln = l & 15;
  const int wr = w >> 1, wc = w & 1;
  const int m0 = blockIdx.x * 128, n0 = blockIdx.y * 128;

  f32x4 acc[4][4];
  #pragma unroll
  for (int i = 0; i < 4; i++)
    #pragma unroll
    for (int j = 0; j < 4; j++) acc[i][j] = (f32x4)0.0f;

  const float* Af = (const float*)Av;
  const short* Ab = (const short*)Av;

  for (int k0 = 0; k0 < 1024; k0 += 32) {
    if constexpr (!A_IS_BF16) {
      #pragma unroll
      for (int i = 0; i < 4; i++) {
        int c = i * 256 + t;
        int row = c >> 3, c4 = c & 7;
        float4v v = *(const float4v*)(Af + (size_t)(m0 + row) * 1024 + k0 + c4 * 4);
        s16x4 p = { f2bf(v.x), f2bf(v.y), f2bf(v.z), f2bf(v.w) };
        *(s16x4*)(&Alds[row * 32 + c4 * 4]) = p;
      }
    } else {
      #pragma unroll
      for (int i = 0; i < 2; i++) {
        int c = i * 256 + t;
        int row = c >> 2, c8 = c & 3;
        *(s16x8*)(&Alds[row * 32 + c8 * 8]) =
            *(const s16x8*)(Ab + (size_t)(m0 + row) * 1024 + k0 + c8 * 8);
      }
    }
    #pragma unroll
    for (int i = 0; i < 4; i++) {
      int c = i * 256 + t;
      int row = c >> 3, c4 = c & 7;
      float4v v = *(const float4v*)(W + (size_t)(n0 + row) * 1024 + k0 + c4 * 4);
      s16x4 p = { f2bf(v.x), f2bf(v.y), f2bf(v.z), f2bf(v.w) };
      *(s16x4*)(&Blds[row * 32 + c4 * 4]) = p;
    }
    __syncthreads();

    s16x8 af[4], bfr[4];
    #pragma unroll
    for (int mf = 0; mf < 4; mf++)
      af[mf] = *(const s16x8*)(&Alds[(wr * 64 + mf * 16 + ln) * 32 + g * 8]);
    #pragma unroll
    for (int nf = 0; nf < 4; nf++)
      bfr[nf] = *(const s16x8*)(&Blds[(wc * 64 + nf * 16 + ln) * 32 + g * 8]);

    #pragma unroll
    for (int mf = 0; mf < 4; mf++)
      #pragma unroll
      for (int nf = 0; nf < 4; nf++)
        acc[mf][nf] = __builtin_amdgcn_mfma_f32_16x16x32_bf16(
            asbf(af[mf]), asbf(bfr[nf]), acc[mf][nf], 0, 0, 0);
    __syncthreads();
  }

  float bv[4];
  #pragma unroll
  for (int nf = 0; nf < 4; nf++) bv[nf] = bias[n0 + wc * 64 + nf * 16 + ln];
  #pragma unroll
  for (int mf = 0; mf < 4; mf++)
    #pragma unroll
    for (int nf = 0; nf < 4; nf++)
      #pragma unroll
      for (int r = 0; r < 4; r++) {
        float vv = (acc[mf][nf][r] + bv[nf]) * scale;
        size_t idx = (size_t)(m0 + wr * 64 + mf * 16 + g * 4 + r) * 1024
                   + n0 + wc * 64 + nf * 16 + ln;
        if constexpr (OUT_IS_F32) ((float*)Cv)[idx] = vv;
        else                      ((short*)Cv)[idx] = f2bf(vv);
      }
}

// ---------------------------------------------------------------------------
// Flash attention v12 (round-12 verified): swapped QK^T, in-register softmax,
// butterfly P-routing, l via MFMA against ones, tree row-max.
// ---------------------------------------------------------------------------
__global__ __launch_bounds__(256, 2) void flash_attn(
    const short* __restrict__ Q, const short* __restrict__ Kswz,
    const short* __restrict__ Vt, short* __restrict__ CTX)
{
  __shared__ short Klds[2][64 * 64];
  __shared__ short Vlds[2][64 * 64];

  const int t  = threadIdx.x;
  const int w  = t >> 6, l = t & 63, g = l >> 4, ln = l & 15;
  const int rb0 = g & 1, rb1 = g >> 1;            // route bits
  const bool sendK = (rb0 ^ rb1) != 0;
  const int bh   = blockIdx.x & 127;               // XCD-local remap
  const int tile = blockIdx.x >> 7;
  const int b = bh >> 4, h = bh & 15;
  const size_t rowbase = (size_t)b * SEQ;
  const int colbase = h * HD;
  const int q0w = tile * 128 + w * 32;

  const short* Kg = Kswz + rowbase * 1024 + colbase;
  const short* Vg = Vt + (size_t)bh * 65536;
  const int c0 = w * 64 + l;

  const short one_bf = (short)0x3F80;              // bf16 1.0
  const s16x8 ones = { one_bf, one_bf, one_bf, one_bf,
                       one_bf, one_bf, one_bf, one_bf };

  s16x8 qf[2][2];
  #pragma unroll
  for (int mf = 0; mf < 2; mf++)
    #pragma unroll
    for (int kf = 0; kf < 2; kf++)
      qf[mf][kf] = *(const s16x8*)(Q + (rowbase + q0w + mf * 16 + ln) * 1024
                                     + colbase + kf * 32 + g * 8);

  f32x4 acc_o[2][4];
  f32x4 l_acc[2];
  #pragma unroll
  for (int i = 0; i < 2; i++) {
    l_acc[i] = (f32x4)0.0f;
    #pragma unroll
    for (int j = 0; j < 4; j++) acc_o[i][j] = (f32x4)0.0f;
  }

  float m_run[2] = { -1e30f, -1e30f };

  auto STAGE = [&](int buf, int nt) {
    #pragma unroll
    for (int i = 0; i < 2; i++) {
      int c = c0 + i * 256;
      gl_lds16(Kg + (size_t)(nt * 64 + (c >> 3)) * 1024 + (c & 7) * 8,
               &Klds[buf][(i * 256 + w * 64) * 8]);
      gl_lds16(Vg + (size_t)(c >> 3) * 1024 + nt * 64 + (c & 7) * 8,
               &Vlds[buf][(i * 256 + w * 64) * 8]);
    }
  };

  STAGE(0, 0);
  __syncthreads();

  int cur = 0;
  for (int kt = 0; kt < 16; kt++) {
    if (kt < 15) STAGE(cur ^ 1, kt + 1);

    const short* Kc = &Klds[cur][0];
    const short* Vc = &Vlds[cur][0];

    // ---- QK^T swapped: sT[kk4][kq]; lane: q=kq*16+ln, k=kk4*16+4g+r ----
    f32x4 sT[4][2];
    #pragma unroll
    for (int i = 0; i < 4; i++)
      #pragma unroll
      for (int j = 0; j < 2; j++) sT[i][j] = (f32x4)0.0f;

    __builtin_amdgcn_s_setprio(1);
    #pragma unroll
    for (int kf = 0; kf < 2; kf++) {
      s16x8 kfr[4];
      #pragma unroll
      for (int nf = 0; nf < 4; nf++)
        kfr[nf] = *(const s16x8*)(Kc + (nf * 16 + ln) * 64
                                     + (((kf * 4 + g) ^ (ln & 7)) * 8));
      #pragma unroll
      for (int kk4 = 0; kk4 < 4; kk4++)
        #pragma unroll
        for (int kq = 0; kq < 2; kq++)
          sT[kk4][kq] = __builtin_amdgcn_mfma_f32_16x16x32_bf16(
              asbf(kfr[kk4]), asbf(qf[kq][kf]), sT[kk4][kq], 0, 0, 0);
    }
    __builtin_amdgcn_s_setprio(0);

    // ---- row max: balanced tree (depth 4) + 2 shfl over g-groups ----
    float rm[2];
    #pragma unroll
    for (int kq = 0; kq < 2; kq++) {
      float a0 = fmaxf(sT[0][kq][0], sT[0][kq][1]);
      float a1 = fmaxf(sT[0][kq][2], sT[0][kq][3]);
      float a2 = fmaxf(sT[1][kq][0], sT[1][kq][1]);
      float a3 = fmaxf(sT[1][kq][2], sT[1][kq][3]);
      float a4 = fmaxf(sT[2][kq][0], sT[2][kq][1]);
      float a5 = fmaxf(sT[2][kq][2], sT[2][kq][3]);
      float a6 = fmaxf(sT[3][kq][0], sT[3][kq][1]);
      float a7 = fmaxf(sT[3][kq][2], sT[3][kq][3]);
      float b0 = fmaxf(a0, a1), b1 = fmaxf(a2, a3);
      float b2 = fmaxf(a4, a5), b3 = fmaxf(a6, a7);
      float mx = fmaxf(fmaxf(b0, b1), fmaxf(b2, b3));
      mx = fmaxf(mx, __shfl_xor(mx, 16));
      mx = fmaxf(mx, __shfl_xor(mx, 32));
      rm[kq] = mx;
    }
    float worst = fmaxf(rm[0] - m_run[0], rm[1] - m_run[1]);

    if (__all(worst <= 8.0f)) {
      #pragma unroll
      for (int kq = 0; kq < 2; kq++) {
        float m0v = m_run[kq];
        #pragma unroll
        for (int kk4 = 0; kk4 < 4; kk4++)
          #pragma unroll
          for (int r = 0; r < 4; r++)
            sT[kk4][kq][r] = exp2f(sT[kk4][kq][r] - m0v);
      }
    } else {
      float sc[2];
      #pragma unroll
      for (int kq = 0; kq < 2; kq++) {
        float mnew = fmaxf(m_run[kq], rm[kq]);
        sc[kq] = exp2f(m_run[kq] - mnew);
        m_run[kq] = mnew;
        #pragma unroll
        for (int kk4 = 0; kk4 < 4; kk4++)
          #pragma unroll
          for (int r = 0; r < 4; r++)
            sT[kk4][kq][r] = exp2f(sT[kk4][kq][r] - mnew);
      }
      // rescale acc_o and l_acc: sc for q = mf*16 + g*4 + r at lane (g*4+r)
      #pragma unroll
      for (int mf = 0; mf < 2; mf++)
        #pragma unroll
        for (int r = 0; r < 4; r++) {
          float scr = __shfl(sc[mf], g * 4 + r);
          l_acc[mf][r] *= scr;
          #pragma unroll
          for (int nf = 0; nf < 4; nf++) acc_o[mf][nf][r] *= scr;
        }
    }

    // ---- pack P to bf16 dword pairs: D[kk4][kq][di] ----
    uint32_t D[4][2][2];
    #pragma unroll
    for (int kk4 = 0; kk4 < 4; kk4++)
      #pragma unroll
      for (int kq = 0; kq < 2; kq++) {
        asm("v_cvt_pk_bf16_f32 %0, %1, %2"
            : "=v"(D[kk4][kq][0]) : "v"(sT[kk4][kq][0]), "v"(sT[kk4][kq][1]));
        asm("v_cvt_pk_bf16_f32 %0, %1, %2"
            : "=v"(D[kk4][kq][1]) : "v"(sT[kk4][kq][2]), "v"(sT[kk4][kq][3]));
      }

    // ---- 2-stage butterfly route -> pa[kq][kp] (PV A-frags) ----
    s16x8 pa[2][2];
    #pragma unroll
    for (int kq = 0; kq < 2; kq++)
      #pragma unroll
      for (int kp = 0; kp < 2; kp++) {
        uint32_t K0 = rb1 ? D[2*kp+1][kq][0] : D[2*kp][kq][0];
        uint32_t K1 = rb1 ? D[2*kp+1][kq][1] : D[2*kp][kq][1];
        uint32_t S0 = rb1 ? D[2*kp][kq][0]   : D[2*kp+1][kq][0];
        uint32_t S1 = rb1 ? D[2*kp][kq][1]   : D[2*kp+1][kq][1];
        uint32_t R0 = (uint32_t)__shfl_xor((int)S0, 32);
        uint32_t R1 = (uint32_t)__shfl_xor((int)S1, 32);
        uint32_t T0 = sendK ? K0 : R0, T1 = sendK ? K1 : R1;
        uint32_t V0 = sendK ? R0 : K0, V1 = sendK ? R1 : K1;
        uint32_t U0 = (uint32_t)__shfl_xor((int)T0, 16);
        uint32_t U1 = (uint32_t)__shfl_xor((int)T1, 16);
        u32x4 dw = { rb0 ? U0 : V0, rb0 ? U1 : V1,
                     rb0 ? V0 : U0, rb0 ? V1 : U1 };
        pa[kq][kp] = __builtin_bit_cast(s16x8, dw);
      }

    // ---- PV (+ l via MFMA against ones) ----
    s16x8 vbf[4][2];
    #pragma unroll
    for (int nf = 0; nf < 4; nf++)
      #pragma unroll
      for (int kf = 0; kf < 2; kf++)
        vbf[nf][kf] = *(const s16x8*)(Vc + (nf * 16 + ln) * 64
                                         + (((kf * 4 + g) ^ (ln & 7)) * 8));

    __builtin_amdgcn_s_setprio(1);
    #pragma unroll
    for (int kf = 0; kf < 2; kf++)
      #pragma unroll
      for (int mf = 0; mf < 2; mf++) {
        l_acc[mf] = __builtin_amdgcn_mfma_f32_16x16x32_bf16(
            asbf(pa[mf][kf]), asbf(ones), l_acc[mf], 0, 0, 0);
        #pragma unroll
        for (int nf = 0; nf < 4; nf++)
          acc_o[mf][nf] = __builtin_amdgcn_mfma_f32_16x16x32_bf16(
              asbf(pa[mf][kf]), asbf(vbf[nf][kf]), acc_o[mf][nf], 0, 0, 0);
      }
    __builtin_amdgcn_s_setprio(0);

    __syncthreads();
    cur ^= 1;
  }

  // ---- finalize: l_acc rows match acc_o rows -> lane-local divide ----
  #pragma unroll
  for (int mf = 0; mf < 2; mf++)
    #pragma unroll
    for (int r = 0; r < 4; r++) {
      float inv = 1.0f / l_acc[mf][r];
      size_t row = rowbase + q0w + mf * 16 + g * 4 + r;
      #pragma unroll
      for (int nf = 0; nf < 4; nf++)
        CTX[row * 1024 + colbase + nf * 16 + ln] = f2bf(acc_o[mf][nf][r] * inv);
    }
}

// ---------------------------------------------------------------------------
// Fallback flash (round-6 proven version): reg-staged K/V, plain layouts.
// ---------------------------------------------------------------------------
__global__ __launch_bounds__(256, 2) void flash_attn_fb(
    const short* __restrict__ Q, const short* __restrict__ K,
    const short* __restrict__ V, short* __restrict__ CTX)
{
  __shared__ short Klds[2][64 * 64];
  __shared__ short Vtl [2][64 * 64];
  __shared__ short Plds[4][32 * 72];

  const int t  = threadIdx.x;
  const int w  = t >> 6, l = t & 63, g = l >> 4, ln = l & 15;
  const int tile = blockIdx.x & 7;
  const int bh   = blockIdx.x >> 3;
  const int b = bh >> 4, h = bh & 15;
  const size_t rowbase = (size_t)b * SEQ;
  const int colbase = h * HD;
  const int q0w = tile * 128 + w * 32;

  const int kk0  = t >> 3;
  const int dblk = t & 7;
  const int ksw  = (dblk ^ (kk0 & 7)) * 8;
  const int kWr  = kk0 * 64 + dblk * 8;
  const short* Kg = K + rowbase * 1024 + colbase + ksw;
  const short* Vg = V + rowbase * 1024 + colbase + dblk * 8;

  s16x8 qf[2][2];
  #pragma unroll
  for (int mf = 0; mf < 2; mf++)
    #pragma unroll
    for (int kf = 0; kf < 2; kf++)
      qf[mf][kf] = *(const s16x8*)(Q + (rowbase + q0w + mf * 16 + ln) * 1024
                                     + colbase + kf * 32 + g * 8);

  f32x4 acc_o[2][4];
  #pragma unroll
  for (int i = 0; i < 2; i++)
    #pragma unroll
    for (int j = 0; j < 4; j++) acc_o[i][j] = (f32x4)0.0f;

  float m_run[2][4], l_run[2][4];
  #pragma unroll
  for (int i = 0; i < 2; i++)
    #pragma unroll
    for (int r = 0; r < 4; r++) { m_run[i][r] = -1e30f; l_run[i][r] = 0.0f; }

  auto storeKV = [&](int buf, s16x8 ka, s16x8 kb, s16x8 va, s16x8 vb8) {
    short* Kd = &Klds[buf][0];
    short* Vd = &Vtl[buf][0];
    *(s16x8*)(Kd + kWr)        = ka;
    *(s16x8*)(Kd + kWr + 2048) = kb;
    #pragma unroll
    for (int e = 0; e < 8; e++) {
      int a0 = (dblk * 8 + e) * 64 + (kk0 ^ ((e ^ dblk) * 8));
      Vd[a0]      = va[e];
      Vd[a0 ^ 32] = vb8[e];
    }
  };

  s16x8 kvA = *(const s16x8*)(Kg + (size_t)kk0 * 1024);
  s16x8 kvB = *(const s16x8*)(Kg + (size_t)(kk0 + 32) * 1024);
  s16x8 vvA = *(const s16x8*)(Vg + (size_t)kk0 * 1024);
  s16x8 vvB = *(const s16x8*)(Vg + (size_t)(kk0 + 32) * 1024);
  storeKV(0, kvA, kvB, vvA, vvB);

  int cur = 0;
  for (int kt = 0; kt < 16; kt++) {
    if (kt < 15) {
      const size_t r0 = (size_t)((kt + 1) * 64 + kk0) * 1024;
      kvA = *(const s16x8*)(Kg + r0);
      kvB = *(const s16x8*)(Kg + r0 + 32 * 1024);
      vvA = *(const s16x8*)(Vg + r0);
      vvB = *(const s16x8*)(Vg + r0 + 32 * 1024);
    }
    __syncthreads();

    const short* Kc = &Klds[cur][0];
    const short* Vc = &Vtl[cur][0];

    f32x4 s_acc[2][4];
    #pragma unroll
    for (int i = 0; i < 2; i++)
      #pragma unroll
      for (int j = 0; j < 4; j++) s_acc[i][j] = (f32x4)0.0f;

    #pragma unroll
    for (int kf = 0; kf < 2; kf++) {
      s16x8 kfr[4];
      #pragma unroll
      for (int nf = 0; nf < 4; nf++)
        kfr[nf] = *(const s16x8*)(Kc + (nf * 16 + ln) * 64
                                     + (((kf * 4 + g) ^ (ln & 7)) * 8));
      #pragma unroll
      for (int mf = 0; mf < 2; mf++)
        #pragma unroll
        for (int nf = 0; nf < 4; nf++)
          s_acc[mf][nf] = __builtin_amdgcn_mfma_f32_16x16x32_bf16(
              asbf(qf[mf][kf]), asbf(kfr[nf]), s_acc[mf][nf], 0, 0, 0);
    }

    float smax[2][4];
    float worst = -1e30f;
    #pragma unroll
    for (int mf = 0; mf < 2; mf++)
      #pragma unroll
      for (int r = 0; r < 4; r++) {
        float mx = fmaxf(fmaxf(s_acc[mf][0][r], s_acc[mf][1][r]),
                         fmaxf(s_acc[mf][2][r], s_acc[mf][3][r]));
        mx = dpp_fmax16(mx);
        smax[mf][r] = mx;
        worst = fmaxf(worst, mx - m_run[mf][r]);
      }

    if (__all(worst <= 8.0f)) {
      #pragma unroll
      for (int mf = 0; mf < 2; mf++)
        #pragma unroll
        for (int r = 0; r < 4; r++) {
          float m0v = m_run[mf][r];
          float rs = 0.0f;
          #pragma unroll
          for (int nf = 0; nf < 4; nf++) {
            float pv = exp2f(s_acc[mf][nf][r] - m0v);
            s_acc[mf][nf][r] = pv;
            rs += pv;
          }
          l_run[mf][r] += rs;
        }
    } else {
      #pragma unroll
      for (int mf = 0; mf < 2; mf++)
        #pragma unroll
        for (int r = 0; r < 4; r++) {
          float mnew = fmaxf(m_run[mf][r], smax[mf][r]);
          float sc = exp2f(m_run[mf][r] - mnew);
          m_run[mf][r] = mnew;
          float rs = 0.0f;
          #pragma unroll
          for (int nf = 0; nf < 4; nf++) {
            float pv = exp2f(s_acc[mf][nf][r] - mnew);
            s_acc[mf][nf][r] = pv;
            rs += pv;
          }
          l_run[mf][r] = l_run[mf][r] * sc + rs;
          #pragma unroll
          for (int nf = 0; nf < 4; nf++) acc_o[mf][nf][r] *= sc;
        }
    }

    short* Pw = &Plds[w][0];
    #pragma unroll
    for (int mf = 0; mf < 2; mf++)
      #pragma unroll
      for (int nf = 0; nf < 4; nf++) {
        uint32_t p01, p23;
        asm("v_cvt_pk_bf16_f32 %0, %1, %2"
            : "=v"(p01) : "v"(s_acc[mf][nf][0]), "v"(s_acc[mf][nf][1]));
        asm("v_cvt_pk_bf16_f32 %0, %1, %2"
            : "=v"(p23) : "v"(s_acc[mf][nf][2]), "v"(s_acc[mf][nf][3]));
        int pb = (mf * 16 + g * 4) * 72 + ((nf * 16 + ln) ^ (g << 3));
        Pw[pb]       = (short)p01;
        Pw[pb + 72]  = (short)(p01 >> 16);
        Pw[pb + 144] = (short)p23;
        Pw[pb + 216] = (short)(p23 >> 16);
      }

    s16x8 pa[2][2], vbf[4][2];
    #pragma unroll
    for (int mf = 0; mf < 2; mf++)
      #pragma unroll
      for (int kf = 0; kf < 2; kf++)
        pa[mf][kf] = *(const s16x8*)(
            &Pw[(mf * 16 + ln) * 72 + (((kf * 4 + g) ^ (ln >> 2)) << 3)]);
    #pragma unroll
    for (int nf = 0; nf < 4; nf++)
      #pragma unroll
      for (int kf = 0; kf < 2; kf++) {
        int d  = nf * 16 + ln;
        int sw = (d & 7) ^ (d >> 3);
        vbf[nf][kf] = *(const s16x8*)(Vc + d * 64 + ((kf * 32 + g * 8) ^ (sw * 8)));
      }

    #pragma unroll
    for (int kf = 0; kf < 2; kf++)
      #pragma unroll
      for (int mf = 0; mf < 2; mf++)
        #pragma unroll
        for (int nf = 0; nf < 4; nf++)
          acc_o[mf][nf] = __builtin_amdgcn_mfma_f32_16x16x32_bf16(
              asbf(pa[mf][kf]), asbf(vbf[nf][kf]), acc_o[mf][nf], 0, 0, 0);

    if (kt < 15) {
      storeKV(cur ^ 1, kvA, kvB, vvA, vvB);
      cur ^= 1;
    }
  }

  #pragma unroll
  for (int mf = 0; mf < 2; mf++)
    #pragma unroll
    for (int r = 0; r < 4; r++) {
      float inv = 1.0f / dpp_fadd16(l_run[mf][r]);
      size_t row = rowbase + q0w + mf * 16 + g * 4 + r;
      #pragma unroll
      for (int nf = 0; nf < 4; nf++)
        CTX[row * 1024 + colbase + nf * 16 + ln] = f2bf(acc_o[mf][nf][r] * inv);
    }
}

// ---------------------------------------------------------------------------
extern "C" void kernel_launch(void* const* d_in, const int* in_sizes, int n_in,
                              void* d_out, int out_size, void* d_ws, size_t ws_size,
                              hipStream_t stream) {
  const float* query = (const float*)d_in[0];
  const float* key   = (const float*)d_in[1];
  const float* value = (const float*)d_in[2];
  const float* Wq = (const float*)d_in[3];
  const float* bq = (const float*)d_in[4];
  const float* Wk = (const float*)d_in[5];
  const float* bk = (const float*)d_in[6];
  const float* Wv = (const float*)d_in[7];
  const float* bv = (const float*)d_in[8];
  const float* Wo = (const float*)d_in[9];
  const float* bo = (const float*)d_in[10];

  const size_t E = (size_t)MTOT * 1024;
  const size_t need_b = (7 * E + 4ull * 1048576) * 2;   // ~125.8 MB (batched)
  const size_t need_s = (5 * E + 4ull * 1048576) * 2;   // ~92.3 MB  (r12 path)

  dim3 gg(MTOT / 128, HIDDEN / 128), bb(256);
  dim3 fg(BATCH * HEADS * (SEQ / 128));

  if (ws_size >= need_b) {
    short* Qb = (short*)d_ws;
    short* Kb = Qb + E;
    short* Vb = Kb + E;
    short* Cx = Vb + E;
    short* T0 = Cx + E;                 // 3 contiguous bf16 inputs
    short* Wb = T0 + 3 * E;

    cvt_w<<<dim3(512, 4), bb, 0, stream>>>(Wq, Wk, Wv, Wo, Wb);
    cvt_x3<<<dim3(4096, 3), bb, 0, stream>>>(query, key, value, T0);
    gemm_qkv<<<dim3(MTOT / 128, HIDDEN / 128, 3), bb, 0, stream>>>(
        T0, Wb, bq, bk, bv, Qb, Kb, Vb);
    vtrans<<<dim3(16, 16, 8), bb, 0, stream>>>(Vb, T0);
    flash_attn<<<fg, bb, 0, stream>>>(Qb, Kb, T0, Cx);
    gemm_bf16_dma<0><<<gg, bb, 0, stream>>>(Cx, Wb + 3 * 1048576, bo,
                                            (float*)d_out, 1.0f);
  } else if (ws_size >= need_s) {
    short* Qb = (short*)d_ws;
    short* Kb = Qb + E;
    short* Vb = Kb + E;
    short* Cx = Vb + E;
    short* T  = Cx + E;
    short* Wb = T  + E;

    cvt_w<<<dim3(512, 4), bb, 0, stream>>>(Wq, Wk, Wv, Wo, Wb);
    cvt_x<<<4096, bb, 0, stream>>>(query, T);
    gemm_bf16_dma<1><<<gg, bb, 0, stream>>>(T, Wb + 0 * 1048576, bq, Qb, QSCALE);
    cvt_x<<<4096, bb, 0, stream>>>(key, T);
    gemm_bf16_dma<2><<<gg, bb, 0, stream>>>(T, Wb + 1 * 1048576, bk, Kb, 1.0f);
    cvt_x<<<4096, bb, 0, stream>>>(value, T);
    gemm_bf16_dma<1><<<gg, bb, 0, stream>>>(T, Wb + 2 * 1048576, bv, Vb, 1.0f);
    vtrans<<<dim3(16, 16, 8), bb, 0, stream>>>(Vb, T);
    flash_attn<<<fg, bb, 0, stream>>>(Qb, Kb, T, Cx);
    gemm_bf16_dma<0><<<gg, bb, 0, stream>>>(Cx, Wb + 3 * 1048576, bo,
                                            (float*)d_out, 1.0f);
  } else {
    short* Qb = (short*)d_ws;
    short* Kb = Qb + E;
    short* Vb = Kb + E;
    short* Cx = Vb + E;

    gemm_bt_bias<false, false><<<gg, bb, 0, stream>>>(query, Wq, bq, Qb, QSCALE);
    gemm_bt_bias<false, false><<<gg, bb, 0, stream>>>(key,   Wk, bk, Kb, 1.0f);
    gemm_bt_bias<false, false><<<gg, bb, 0, stream>>>(value, Wv, bv, Vb, 1.0f);
    flash_attn_fb<<<fg, bb, 0, stream>>>(Qb, Kb, Vb, Cx);
    gemm_bt_bias<true, true><<<gg, bb, 0, stream>>>(Cx, Wo, bo, (float*)d_out, 1.0f);
  }
}

// Round 15
// 204.290 us; speedup vs baseline: 1.0970x; 1.0403x over previous
//
#include <hip/hip_runtime.h>
#include <hip/hip_bf16.h>
#include <stdint.h>

#define HIDDEN 1024
#define HEADS 16
#define HD 64
#define BATCH 8
#define SEQ 1024
#define MTOT (BATCH*SEQ)   // 8192 rows total

typedef __attribute__((ext_vector_type(4))) float  f32x4;
typedef __attribute__((ext_vector_type(4))) float  float4v;
typedef __attribute__((ext_vector_type(8))) short  s16x8;
typedef __attribute__((ext_vector_type(4))) short  s16x4;
typedef __attribute__((ext_vector_type(4))) unsigned int u32x4;
typedef __bf16 bf16x8 __attribute__((ext_vector_type(8)));

// log2(e) / sqrt(HEAD_DIM)
#define QSCALE 0.18033688011112042f

__device__ __forceinline__ short f2bf(float f) {
  uint32_t u = __builtin_bit_cast(uint32_t, f);
  u += 0x7FFFu + ((u >> 16) & 1u);          // RNE to bf16
  return (short)(u >> 16);
}
__device__ __forceinline__ bf16x8 asbf(s16x8 v) {
  return __builtin_bit_cast(bf16x8, v);
}

// ---- DPP 16-lane reductions (VALU only) -----------------------------------
__device__ __forceinline__ float dpp_fmax16(float x) {
  int t;
  t = __builtin_amdgcn_update_dpp(0, __builtin_bit_cast(int, x), 0xB1, 0xF, 0xF, true);
  x = fmaxf(x, __builtin_bit_cast(float, t));
  t = __builtin_amdgcn_update_dpp(0, __builtin_bit_cast(int, x), 0x4E, 0xF, 0xF, true);
  x = fmaxf(x, __builtin_bit_cast(float, t));
  t = __builtin_amdgcn_update_dpp(0, __builtin_bit_cast(int, x), 0x141, 0xF, 0xF, true);
  x = fmaxf(x, __builtin_bit_cast(float, t));
  t = __builtin_amdgcn_update_dpp(0, __builtin_bit_cast(int, x), 0x140, 0xF, 0xF, true);
  x = fmaxf(x, __builtin_bit_cast(float, t));
  return x;
}
__device__ __forceinline__ float dpp_fadd16(float x) {
  int t;
  t = __builtin_amdgcn_update_dpp(0, __builtin_bit_cast(int, x), 0xB1, 0xF, 0xF, true);
  x += __builtin_bit_cast(float, t);
  t = __builtin_amdgcn_update_dpp(0, __builtin_bit_cast(int, x), 0x4E, 0xF, 0xF, true);
  x += __builtin_bit_cast(float, t);
  t = __builtin_amdgcn_update_dpp(0, __builtin_bit_cast(int, x), 0x141, 0xF, 0xF, true);
  x += __builtin_bit_cast(float, t);
  t = __builtin_amdgcn_update_dpp(0, __builtin_bit_cast(int, x), 0x140, 0xF, 0xF, true);
  x += __builtin_bit_cast(float, t);
  return x;
}

// global -> LDS direct DMA, 16 B per lane.
typedef const __attribute__((address_space(1))) void* gvp;
typedef __attribute__((address_space(3)))       void* lvp;
__device__ __forceinline__ void gl_lds16(const void* g, const void* ldsbase) {
  __builtin_amdgcn_global_load_lds((gvp)(uintptr_t)g,
                                   (lvp)(uintptr_t)(uint32_t)(uintptr_t)ldsbase,
                                   16, 0, 0);
}

// ---------------------------------------------------------------------------
// fp32 -> bf16 converters. GEMM-input producers apply the BK=64 staging
// swizzle: within each 64-col group, 8-elem chunk sub ^= (row & 7).
// (global_load_lds copies linearly; pre-swizzling the source makes the
//  BK=64 LDS tile conflict-free on b128 frag reads — rule "both sides".)
// ---------------------------------------------------------------------------
__global__ __launch_bounds__(256) void cvt_x(const float* __restrict__ src,
                                             short* __restrict__ dst) {
  int i = blockIdx.x * 256 + threadIdx.x;
  int row = i >> 7, c = i & 127;
  int group = c >> 3, sub = (c & 7) ^ (row & 7);
  float4v a = *(const float4v*)(src + (size_t)i * 8);
  float4v b = *(const float4v*)(src + (size_t)i * 8 + 4);
  s16x8 o = { f2bf(a.x), f2bf(a.y), f2bf(a.z), f2bf(a.w),
              f2bf(b.x), f2bf(b.y), f2bf(b.z), f2bf(b.w) };
  *(s16x8*)(dst + (size_t)row * 1024 + group * 64 + sub * 8) = o;
}

// batched: z = 0/1/2 -> query/key/value, dst = T + z*E (swizzled)
__global__ __launch_bounds__(256) void cvt_x3(const float* __restrict__ s0,
                                              const float* __restrict__ s1,
                                              const float* __restrict__ s2,
                                              short* __restrict__ dst) {
  int z = blockIdx.y;
  const float* src = (z == 0) ? s0 : (z == 1) ? s1 : s2;
  int i = blockIdx.x * 256 + threadIdx.x;
  int row = i >> 7, c = i & 127;
  int group = c >> 3, sub = (c & 7) ^ (row & 7);
  float4v a = *(const float4v*)(src + (size_t)i * 8);
  float4v b = *(const float4v*)(src + (size_t)i * 8 + 4);
  s16x8 o = { f2bf(a.x), f2bf(a.y), f2bf(a.z), f2bf(a.w),
              f2bf(b.x), f2bf(b.y), f2bf(b.z), f2bf(b.w) };
  *(s16x8*)(dst + (size_t)z * ((size_t)MTOT * 1024)
                + (size_t)row * 1024 + group * 64 + sub * 8) = o;
}

__global__ __launch_bounds__(256) void cvt_w(const float* __restrict__ s0,
                                             const float* __restrict__ s1,
                                             const float* __restrict__ s2,
                                             const float* __restrict__ s3,
                                             short* __restrict__ dst) {
  int z = blockIdx.y;
  const float* src = (z == 0) ? s0 : (z == 1) ? s1 : (z == 2) ? s2 : s3;
  int i = blockIdx.x * 256 + threadIdx.x;
  int row = i >> 7, c = i & 127;
  int group = c >> 3, sub = (c & 7) ^ (row & 7);
  float4v a = *(const float4v*)(src + (size_t)i * 8);
  float4v b = *(const float4v*)(src + (size_t)i * 8 + 4);
  s16x8 o = { f2bf(a.x), f2bf(a.y), f2bf(a.z), f2bf(a.w),
              f2bf(b.x), f2bf(b.y), f2bf(b.z), f2bf(b.w) };
  *(s16x8*)(dst + (size_t)z * 1048576
                + (size_t)row * 1024 + group * 64 + sub * 8) = o;
}

// ---------------------------------------------------------------------------
// V transpose: Vb[s][h*64+d] -> Vt[(b*16+h)*64+d][s], with flash's k-block
// swizzle (block ^= d&7) pre-applied per 64-k tile. Coalesced both sides.
// ---------------------------------------------------------------------------
__global__ __launch_bounds__(256) void vtrans(const short* __restrict__ Vb,
                                              short* __restrict__ Vt) {
  __shared__ short lt[64 * 64];
  const int t = threadIdx.x;
  const int kt0 = blockIdx.x, h = blockIdx.y, b = blockIdx.z;
  const short* src = Vb + ((size_t)(b * 1024 + kt0 * 64)) * 1024 + h * 64;

  #pragma unroll
  for (int i = 0; i < 2; i++) {
    int c = t + i * 256;
    int s = c >> 3, dc = c & 7;
    s16x8 v = *(const s16x8*)(src + (size_t)s * 1024 + dc * 8);
    int dcp = dc ^ (s & 7) ^ ((s >> 3) & 7);
    *(s16x8*)(&lt[s * 64 + dcp * 8]) = v;
  }
  __syncthreads();

  short* dst = Vt + ((size_t)(b * 16 + h) * 64) * 1024 + kt0 * 64;
  #pragma unroll
  for (int i = 0; i < 2; i++) {
    int c = t + i * 256;
    int d = c >> 3, kc = c & 7;
    s16x8 o;
    #pragma unroll
    for (int j = 0; j < 8; j++) {
      int s = kc * 8 + j;
      o[j] = lt[s * 64 + (((d >> 3) ^ j ^ kc) * 8) + (d & 7)];
    }
    *(s16x8*)(dst + (size_t)d * 1024 + (kc ^ (d & 7)) * 8) = o;
  }
}

// ---------------------------------------------------------------------------
// GEMM core v15: BK=64 (16 K-iters, half the barrier/drain count of BK=32),
// 4-wave 128x128 tile, DMA staging from PRE-SWIZZLED inputs (chunk sub ^=
// row&7 per 64-col group). Frag reads at block (kf*4+g)^(ln&7): 8 distinct
// 16B slots x 2 lanes = 2-way (free). LDS 2x32KB.
// Template CMODE: 0 = f32 out, 1 = bf16 out, 2 = bf16 out + flash K-col
// swizzle. Outputs are TRUE layout (+K swizzle) — flash inputs unchanged.
// ---------------------------------------------------------------------------
template<int CMODE>
__global__ __launch_bounds__(256, 2) void gemm_bf16_dma(
    const short* __restrict__ A, const short* __restrict__ Wb,
    const float* __restrict__ bias, void* __restrict__ Cv, float scale)
{
  __shared__ short Alds[128 * 64];
  __shared__ short Blds[128 * 64];

  const int t  = threadIdx.x;
  const int w  = t >> 6, l = t & 63, g = l >> 4, ln = l & 15;
  const int wr = w >> 1, wc = w & 1;
  const int m0 = blockIdx.x * 128, n0 = blockIdx.y * 128;

  f32x4 acc[4][4];
  #pragma unroll
  for (int i = 0; i < 4; i++)
    #pragma unroll
    for (int j = 0; j < 4; j++) acc[i][j] = (f32x4)0.0f;

  for (int k0 = 0; k0 < 1024; k0 += 64) {
    #pragma unroll
    for (int i = 0; i < 4; i++) {
      int c = i * 256 + w * 64 + l;            // 1024 chunks of 16B per tile
      int row = c >> 3, cb = c & 7;
      gl_lds16(A  + (size_t)(m0 + row) * 1024 + k0 + cb * 8,
               &Alds[(i * 256 + w * 64) * 8]);
      gl_lds16(Wb + (size_t)(n0 + row) * 1024 + k0 + cb * 8,
               &Blds[(i * 256 + w * 64) * 8]);
    }
    __syncthreads();

    #pragma unroll
    for (int kf = 0; kf < 2; kf++) {
      s16x8 af[4], bfr[4];
      #pragma unroll
      for (int mf = 0; mf < 4; mf++) {
        int row = wr * 64 + mf * 16 + ln;
        af[mf] = *(const s16x8*)(&Alds[row * 64 + (((kf * 4 + g) ^ (ln & 7)) * 8)]);
      }
      #pragma unroll
      for (int nf = 0; nf < 4; nf++) {
        int row = wc * 64 + nf * 16 + ln;
        bfr[nf] = *(const s16x8*)(&Blds[row * 64 + (((kf * 4 + g) ^ (ln & 7)) * 8)]);
      }

      __builtin_amdgcn_s_setprio(1);
      #pragma unroll
      for (int mf = 0; mf < 4; mf++)
        #pragma unroll
        for (int nf = 0; nf < 4; nf++)
          acc[mf][nf] = __builtin_amdgcn_mfma_f32_16x16x32_bf16(
              asbf(af[mf]), asbf(bfr[nf]), acc[mf][nf], 0, 0, 0);
      __builtin_amdgcn_s_setprio(0);
    }
    __syncthreads();
  }

  float bv[4];
  #pragma unroll
  for (int nf = 0; nf < 4; nf++) bv[nf] = bias[n0 + wc * 64 + nf * 16 + ln];
  #pragma unroll
  for (int mf = 0; mf < 4; mf++)
    #pragma unroll
    for (int nf = 0; nf < 4; nf++)
      #pragma unroll
      for (int r = 0; r < 4; r++) {
        float vv = (acc[mf][nf][r] + bv[nf]) * scale;
        size_t idx = (size_t)(m0 + wr * 64 + mf * 16 + g * 4 + r) * 1024
                   + n0 + wc * 64 + nf * 16 + ln;
        if constexpr (CMODE == 0) ((float*)Cv)[idx] = vv;
        else if constexpr (CMODE == 1) ((short*)Cv)[idx] = f2bf(vv);
        else {
          size_t idxs = idx ^ (size_t)(((g * 4 + r) & 7) * 8);  // col^8*(row&7)
          ((short*)Cv)[idxs] = f2bf(vv);
        }
      }
}

// ---------------------------------------------------------------------------
// z-batched Q/K/V projection GEMM (BK=64, swizzled staging as above).
// z==1 (K) applies flash K-col output swizzle; z==0 (Q) applies QSCALE.
// ---------------------------------------------------------------------------
__global__ __launch_bounds__(256, 2) void gemm_qkv(
    const short* __restrict__ X3, const short* __restrict__ Wb,
    const float* __restrict__ bq, const float* __restrict__ bk,
    const float* __restrict__ bv_, short* __restrict__ Qb,
    short* __restrict__ Kb, short* __restrict__ Vb)
{
  __shared__ short Alds[128 * 64];
  __shared__ short Blds[128 * 64];

  const size_t E = (size_t)MTOT * 1024;
  const int z = blockIdx.z;
  const short* A  = X3 + (size_t)z * E;
  const short* W  = Wb + (size_t)z * 1048576;
  const float* bias = (z == 0) ? bq : (z == 1) ? bk : bv_;
  short* Cv = (z == 0) ? Qb : (z == 1) ? Kb : Vb;
  const float scale = (z == 0) ? QSCALE : 1.0f;
  const bool kswz = (z == 1);

  const int t  = threadIdx.x;
  const int w  = t >> 6, l = t & 63, g = l >> 4, ln = l & 15;
  const int wr = w >> 1, wc = w & 1;
  const int m0 = blockIdx.x * 128, n0 = blockIdx.y * 128;

  f32x4 acc[4][4];
  #pragma unroll
  for (int i = 0; i < 4; i++)
    #pragma unroll
    for (int j = 0; j < 4; j++) acc[i][j] = (f32x4)0.0f;

  for (int k0 = 0; k0 < 1024; k0 += 64) {
    #pragma unroll
    for (int i = 0; i < 4; i++) {
      int c = i * 256 + w * 64 + l;
      int row = c >> 3, cb = c & 7;
      gl_lds16(A + (size_t)(m0 + row) * 1024 + k0 + cb * 8,
               &Alds[(i * 256 + w * 64) * 8]);
      gl_lds16(W + (size_t)(n0 + row) * 1024 + k0 + cb * 8,
               &Blds[(i * 256 + w * 64) * 8]);
    }
    __syncthreads();

    #pragma unroll
    for (int kf = 0; kf < 2; kf++) {
      s16x8 af[4], bfr[4];
      #pragma unroll
      for (int mf = 0; mf < 4; mf++) {
        int row = wr * 64 + mf * 16 + ln;
        af[mf] = *(const s16x8*)(&Alds[row * 64 + (((kf * 4 + g) ^ (ln & 7)) * 8)]);
      }
      #pragma unroll
      for (int nf = 0; nf < 4; nf++) {
        int row = wc * 64 + nf * 16 + ln;
        bfr[nf] = *(const s16x8*)(&Blds[row * 64 + (((kf * 4 + g) ^ (ln & 7)) * 8)]);
      }

      __builtin_amdgcn_s_setprio(1);
      #pragma unroll
      for (int mf = 0; mf < 4; mf++)
        #pragma unroll
        for (int nf = 0; nf < 4; nf++)
          acc[mf][nf] = __builtin_amdgcn_mfma_f32_16x16x32_bf16(
              asbf(af[mf]), asbf(bfr[nf]), acc[mf][nf], 0, 0, 0);
      __builtin_amdgcn_s_setprio(0);
    }
    __syncthreads();
  }

  float bv[4];
  #pragma unroll
  for (int nf = 0; nf < 4; nf++) bv[nf] = bias[n0 + wc * 64 + nf * 16 + ln];
  #pragma unroll
  for (int mf = 0; mf < 4; mf++)
    #pragma unroll
    for (int nf = 0; nf < 4; nf++)
      #pragma unroll
      for (int r = 0; r < 4; r++) {
        float vv = (acc[mf][nf][r] + bv[nf]) * scale;
        size_t idx = (size_t)(m0 + wr * 64 + mf * 16 + g * 4 + r) * 1024
                   + n0 + wc * 64 + nf * 16 + ln;
        if (kswz) idx ^= (size_t)(((g * 4 + r) & 7) * 8);
        Cv[idx] = f2bf(vv);
      }
}

// ---------------------------------------------------------------------------
// Fallback GEMM (reg-staged conversion, TRUE layouts), unchanged.
// ---------------------------------------------------------------------------
template<bool A_IS_BF16, bool OUT_IS_F32>
__global__ __launch_bounds__(256, 2) void gemm_bt_bias(
    const void* __restrict__ Av, const float* __restrict__ W,
    const float* __restrict__ bias, void* __restrict__ Cv, float scale)
{
  __shared__ short Alds[128 * 32];
  __shared__ short Blds[128 * 32];

  const int t  = threadIdx.x;
  const int w  = t >> 6, l = t & 63, g = l >> 4, ln = l & 15;
  const int wr = w >> 1, wc = w & 1;
  const int m0 = blockIdx.x * 128, n0 = blockIdx.y * 128;

  f32x4 acc[4][4];
  #pragma unroll
  for (int i = 0; i < 4; i++)
    #pragma unroll
    for (int j = 0; j < 4; j++) acc[i][j] = (f32x4)0.0f;

  const float* Af = (const float*)Av;
  const short* Ab = (const short*)Av;

  for (int k0 = 0; k0 < 1024; k0 += 32) {
    if constexpr (!A_IS_BF16) {
      #pragma unroll
      for (int i = 0; i < 4; i++) {
        int c = i * 256 + t;
        int row = c >> 3, c4 = c & 7;
        float4v v = *(const float4v*)(Af + (size_t)(m0 + row) * 1024 + k0 + c4 * 4);
        s16x4 p = { f2bf(v.x), f2bf(v.y), f2bf(v.z), f2bf(v.w) };
        *(s16x4*)(&Alds[row * 32 + c4 * 4]) = p;
      }
    } else {
      #pragma unroll
      for (int i = 0; i < 2; i++) {
        int c = i * 256 + t;
        int row = c >> 2, c8 = c & 3;
        *(s16x8*)(&Alds[row * 32 + c8 * 8]) =
            *(const s16x8*)(Ab + (size_t)(m0 + row) * 1024 + k0 + c8 * 8);
      }
    }
    #pragma unroll
    for (int i = 0; i < 4; i++) {
      int c = i * 256 + t;
      int row = c >> 3, c4 = c & 7;
      float4v v = *(const float4v*)(W + (size_t)(n0 + row) * 1024 + k0 + c4 * 4);
      s16x4 p = { f2bf(v.x), f2bf(v.y), f2bf(v.z), f2bf(v.w) };
      *(s16x4*)(&Blds[row * 32 + c4 * 4]) = p;
    }
    __syncthreads();

    s16x8 af[4], bfr[4];
    #pragma unroll
    for (int mf = 0; mf < 4; mf++)
      af[mf] = *(const s16x8*)(&Alds[(wr * 64 + mf * 16 + ln) * 32 + g * 8]);
    #pragma unroll
    for (int nf = 0; nf < 4; nf++)
      bfr[nf] = *(const s16x8*)(&Blds[(wc * 64 + nf * 16 + ln) * 32 + g * 8]);

    #pragma unroll
    for (int mf = 0; mf < 4; mf++)
      #pragma unroll
      for (int nf = 0; nf < 4; nf++)
        acc[mf][nf] = __builtin_amdgcn_mfma_f32_16x16x32_bf16(
            asbf(af[mf]), asbf(bfr[nf]), acc[mf][nf], 0, 0, 0);
    __syncthreads();
  }

  float bv[4];
  #pragma unroll
  for (int nf = 0; nf < 4; nf++) bv[nf] = bias[n0 + wc * 64 + nf * 16 + ln];
  #pragma unroll
  for (int mf = 0; mf < 4; mf++)
    #pragma unroll
    for (int nf = 0; nf < 4; nf++)
      #pragma unroll
      for (int r = 0; r < 4; r++) {
        float vv = (acc[mf][nf][r] + bv[nf]) * scale;
        size_t idx = (size_t)(m0 + wr * 64 + mf * 16 + g * 4 + r) * 1024
                   + n0 + wc * 64 + nf * 16 + ln;
        if constexpr (OUT_IS_F32) ((float*)Cv)[idx] = vv;
        else                      ((short*)Cv)[idx] = f2bf(vv);
      }
}

// ---------------------------------------------------------------------------
// Flash attention v12 + CTX written in BK=64-swizzled layout (block tb ^=
// row&7 within 64-col group) so the final GEMM can DMA-stage it directly.
// ---------------------------------------------------------------------------
__global__ __launch_bounds__(256, 2) void flash_attn(
    const short* __restrict__ Q, const short* __restrict__ Kswz,
    const short* __restrict__ Vt, short* __restrict__ CTX)
{
  __shared__ short Klds[2][64 * 64];
  __shared__ short Vlds[2][64 * 64];

  const int t  = threadIdx.x;
  const int w  = t >> 6, l = t & 63, g = l >> 4, ln = l & 15;
  const int rb0 = g & 1, rb1 = g >> 1;            // route bits
  const bool sendK = (rb0 ^ rb1) != 0;
  const int bh   = blockIdx.x & 127;               // XCD-local remap
  const int tile = blockIdx.x >> 7;
  const int b = bh >> 4, h = bh & 15;
  const size_t rowbase = (size_t)b * SEQ;
  const int colbase = h * HD;
  const int q0w = tile * 128 + w * 32;

  const short* Kg = Kswz + rowbase * 1024 + colbase;
  const short* Vg = Vt + (size_t)bh * 65536;
  const int c0 = w * 64 + l;

  const short one_bf = (short)0x3F80;              // bf16 1.0
  const s16x8 ones = { one_bf, one_bf, one_bf, one_bf,
                       one_bf, one_bf, one_bf, one_bf };

  s16x8 qf[2][2];
  #pragma unroll
  for (int mf = 0; mf < 2; mf++)
    #pragma unroll
    for (int kf = 0; kf < 2; kf++)
      qf[mf][kf] = *(const s16x8*)(Q + (rowbase + q0w + mf * 16 + ln) * 1024
                                     + colbase + kf * 32 + g * 8);

  f32x4 acc_o[2][4];
  f32x4 l_acc[2];
  #pragma unroll
  for (int i = 0; i < 2; i++) {
    l_acc[i] = (f32x4)0.0f;
    #pragma unroll
    for (int j = 0; j < 4; j++) acc_o[i][j] = (f32x4)0.0f;
  }

  float m_run[2] = { -1e30f, -1e30f };

  auto STAGE = [&](int buf, int nt) {
    #pragma unroll
    for (int i = 0; i < 2; i++) {
      int c = c0 + i * 256;
      gl_lds16(Kg + (size_t)(nt * 64 + (c >> 3)) * 1024 + (c & 7) * 8,
               &Klds[buf][(i * 256 + w * 64) * 8]);
      gl_lds16(Vg + (size_t)(c >> 3) * 1024 + nt * 64 + (c & 7) * 8,
               &Vlds[buf][(i * 256 + w * 64) * 8]);
    }
  };

  STAGE(0, 0);
  __syncthreads();

  int cur = 0;
  for (int kt = 0; kt < 16; kt++) {
    if (kt < 15) STAGE(cur ^ 1, kt + 1);

    const short* Kc = &Klds[cur][0];
    const short* Vc = &Vlds[cur][0];

    // ---- QK^T swapped: sT[kk4][kq]; lane: q=kq*16+ln, k=kk4*16+4g+r ----
    f32x4 sT[4][2];
    #pragma unroll
    for (int i = 0; i < 4; i++)
      #pragma unroll
      for (int j = 0; j < 2; j++) sT[i][j] = (f32x4)0.0f;

    __builtin_amdgcn_s_setprio(1);
    #pragma unroll
    for (int kf = 0; kf < 2; kf++) {
      s16x8 kfr[4];
      #pragma unroll
      for (int nf = 0; nf < 4; nf++)
        kfr[nf] = *(const s16x8*)(Kc + (nf * 16 + ln) * 64
                                     + (((kf * 4 + g) ^ (ln & 7)) * 8));
      #pragma unroll
      for (int kk4 = 0; kk4 < 4; kk4++)
        #pragma unroll
        for (int kq = 0; kq < 2; kq++)
          sT[kk4][kq] = __builtin_amdgcn_mfma_f32_16x16x32_bf16(
              asbf(kfr[kk4]), asbf(qf[kq][kf]), sT[kk4][kq], 0, 0, 0);
    }
    __builtin_amdgcn_s_setprio(0);

    // ---- row max: balanced tree (depth 4) + 2 shfl over g-groups ----
    float rm[2];
    #pragma unroll
    for (int kq = 0; kq < 2; kq++) {
      float a0 = fmaxf(sT[0][kq][0], sT[0][kq][1]);
      float a1 = fmaxf(sT[0][kq][2], sT[0][kq][3]);
      float a2 = fmaxf(sT[1][kq][0], sT[1][kq][1]);
      float a3 = fmaxf(sT[1][kq][2], sT[1][kq][3]);
      float a4 = fmaxf(sT[2][kq][0], sT[2][kq][1]);
      float a5 = fmaxf(sT[2][kq][2], sT[2][kq][3]);
      float a6 = fmaxf(sT[3][kq][0], sT[3][kq][1]);
      float a7 = fmaxf(sT[3][kq][2], sT[3][kq][3]);
      float b0 = fmaxf(a0, a1), b1 = fmaxf(a2, a3);
      float b2 = fmaxf(a4, a5), b3 = fmaxf(a6, a7);
      float mx = fmaxf(fmaxf(b0, b1), fmaxf(b2, b3));
      mx = fmaxf(mx, __shfl_xor(mx, 16));
      mx = fmaxf(mx, __shfl_xor(mx, 32));
      rm[kq] = mx;
    }
    float worst = fmaxf(rm[0] - m_run[0], rm[1] - m_run[1]);

    if (__all(worst <= 8.0f)) {
      #pragma unroll
      for (int kq = 0; kq < 2; kq++) {
        float m0v = m_run[kq];
        #pragma unroll
        for (int kk4 = 0; kk4 < 4; kk4++)
          #pragma unroll
          for (int r = 0; r < 4; r++)
            sT[kk4][kq][r] = exp2f(sT[kk4][kq][r] - m0v);
      }
    } else {
      float sc[2];
      #pragma unroll
      for (int kq = 0; kq < 2; kq++) {
        float mnew = fmaxf(m_run[kq], rm[kq]);
        sc[kq] = exp2f(m_run[kq] - mnew);
        m_run[kq] = mnew;
        #pragma unroll
        for (int kk4 = 0; kk4 < 4; kk4++)
          #pragma unroll
          for (int r = 0; r < 4; r++)
            sT[kk4][kq][r] = exp2f(sT[kk4][kq][r] - mnew);
      }
      // rescale acc_o and l_acc: sc for q = mf*16 + g*4 + r at lane (g*4+r)
      #pragma unroll
      for (int mf = 0; mf < 2; mf++)
        #pragma unroll
        for (int r = 0; r < 4; r++) {
          float scr = __shfl(sc[mf], g * 4 + r);
          l_acc[mf][r] *= scr;
          #pragma unroll
          for (int nf = 0; nf < 4; nf++) acc_o[mf][nf][r] *= scr;
        }
    }

    // ---- pack P to bf16 dword pairs: D[kk4][kq][di] ----
    uint32_t D[4][2][2];
    #pragma unroll
    for (int kk4 = 0; kk4 < 4; kk4++)
      #pragma unroll
      for (int kq = 0; kq < 2; kq++) {
        asm("v_cvt_pk_bf16_f32 %0, %1, %2"
            : "=v"(D[kk4][kq][0]) : "v"(sT[kk4][kq][0]), "v"(sT[kk4][kq][1]));
        asm("v_cvt_pk_bf16_f32 %0, %1, %2"
            : "=v"(D[kk4][kq][1]) : "v"(sT[kk4][kq][2]), "v"(sT[kk4][kq][3]));
      }

    // ---- 2-stage butterfly route -> pa[kq][kp] (PV A-frags) ----
    s16x8 pa[2][2];
    #pragma unroll
    for (int kq = 0; kq < 2; kq++)
      #pragma unroll
      for (int kp = 0; kp < 2; kp++) {
        uint32_t K0 = rb1 ? D[2*kp+1][kq][0] : D[2*kp][kq][0];
        uint32_t K1 = rb1 ? D[2*kp+1][kq][1] : D[2*kp][kq][1];
        uint32_t S0 = rb1 ? D[2*kp][kq][0]   : D[2*kp+1][kq][0];
        uint32_t S1 = rb1 ? D[2*kp][kq][1]   : D[2*kp+1][kq][1];
        uint32_t R0 = (uint32_t)__shfl_xor((int)S0, 32);
        uint32_t R1 = (uint32_t)__shfl_xor((int)S1, 32);
        uint32_t T0 = sendK ? K0 : R0, T1 = sendK ? K1 : R1;
        uint32_t V0 = sendK ? R0 : K0, V1 = sendK ? R1 : K1;
        uint32_t U0 = (uint32_t)__shfl_xor((int)T0, 16);
        uint32_t U1 = (uint32_t)__shfl_xor((int)T1, 16);
        u32x4 dw = { rb0 ? U0 : V0, rb0 ? U1 : V1,
                     rb0 ? V0 : U0, rb0 ? V1 : U1 };
        pa[kq][kp] = __builtin_bit_cast(s16x8, dw);
      }

    // ---- PV (+ l via MFMA against ones) ----
    s16x8 vbf[4][2];
    #pragma unroll
    for (int nf = 0; nf < 4; nf++)
      #pragma unroll
      for (int kf = 0; kf < 2; kf++)
        vbf[nf][kf] = *(const s16x8*)(Vc + (nf * 16 + ln) * 64
                                         + (((kf * 4 + g) ^ (ln & 7)) * 8));

    __builtin_amdgcn_s_setprio(1);
    #pragma unroll
    for (int kf = 0; kf < 2; kf++)
      #pragma unroll
      for (int mf = 0; mf < 2; mf++) {
        l_acc[mf] = __builtin_amdgcn_mfma_f32_16x16x32_bf16(
            asbf(pa[mf][kf]), asbf(ones), l_acc[mf], 0, 0, 0);
        #pragma unroll
        for (int nf = 0; nf < 4; nf++)
          acc_o[mf][nf] = __builtin_amdgcn_mfma_f32_16x16x32_bf16(
              asbf(pa[mf][kf]), asbf(vbf[nf][kf]), acc_o[mf][nf], 0, 0, 0);
      }
    __builtin_amdgcn_s_setprio(0);

    __syncthreads();
    cur ^= 1;
  }

  // ---- finalize: lane-local divide; store CTX in BK=64-swizzled layout ----
  #pragma unroll
  for (int mf = 0; mf < 2; mf++)
    #pragma unroll
    for (int r = 0; r < 4; r++) {
      float inv = 1.0f / l_acc[mf][r];
      size_t row = rowbase + q0w + mf * 16 + g * 4 + r;
      int rs = (g * 4 + r) & 7;                       // row & 7
      #pragma unroll
      for (int nf = 0; nf < 4; nf++) {
        int tc = nf * 16 + ln;                        // true col in 64-group
        int sb = (tc >> 3) ^ rs;                      // swizzled 8-col block
        CTX[row * 1024 + colbase + sb * 8 + (tc & 7)] =
            f2bf(acc_o[mf][nf][r] * inv);
      }
    }
}

// ---------------------------------------------------------------------------
// Fallback flash (round-6 proven version): reg-staged K/V, plain layouts.
// ---------------------------------------------------------------------------
__global__ __launch_bounds__(256, 2) void flash_attn_fb(
    const short* __restrict__ Q, const short* __restrict__ K,
    const short* __restrict__ V, short* __restrict__ CTX)
{
  __shared__ short Klds[2][64 * 64];
  __shared__ short Vtl [2][64 * 64];
  __shared__ short Plds[4][32 * 72];

  const int t  = threadIdx.x;
  const int w  = t >> 6, l = t & 63, g = l >> 4, ln = l & 15;
  const int tile = blockIdx.x & 7;
  const int bh   = blockIdx.x >> 3;
  const int b = bh >> 4, h = bh & 15;
  const size_t rowbase = (size_t)b * SEQ;
  const int colbase = h * HD;
  const int q0w = tile * 128 + w * 32;

  const int kk0  = t >> 3;
  const int dblk = t & 7;
  const int ksw  = (dblk ^ (kk0 & 7)) * 8;
  const int kWr  = kk0 * 64 + dblk * 8;
  const short* Kg = K + rowbase * 1024 + colbase + ksw;
  const short* Vg = V + rowbase * 1024 + colbase + dblk * 8;

  s16x8 qf[2][2];
  #pragma unroll
  for (int mf = 0; mf < 2; mf++)
    #pragma unroll
    for (int kf = 0; kf < 2; kf++)
      qf[mf][kf] = *(const s16x8*)(Q + (rowbase + q0w + mf * 16 + ln) * 1024
                                     + colbase + kf * 32 + g * 8);

  f32x4 acc_o[2][4];
  #pragma unroll
  for (int i = 0; i < 2; i++)
    #pragma unroll
    for (int j = 0; j < 4; j++) acc_o[i][j] = (f32x4)0.0f;

  float m_run[2][4], l_run[2][4];
  #pragma unroll
  for (int i = 0; i < 2; i++)
    #pragma unroll
    for (int r = 0; r < 4; r++) { m_run[i][r] = -1e30f; l_run[i][r] = 0.0f; }

  auto storeKV = [&](int buf, s16x8 ka, s16x8 kb, s16x8 va, s16x8 vb8) {
    short* Kd = &Klds[buf][0];
    short* Vd = &Vtl[buf][0];
    *(s16x8*)(Kd + kWr)        = ka;
    *(s16x8*)(Kd + kWr + 2048) = kb;
    #pragma unroll
    for (int e = 0; e < 8; e++) {
      int a0 = (dblk * 8 + e) * 64 + (kk0 ^ ((e ^ dblk) * 8));
      Vd[a0]      = va[e];
      Vd[a0 ^ 32] = vb8[e];
    }
  };

  s16x8 kvA = *(const s16x8*)(Kg + (size_t)kk0 * 1024);
  s16x8 kvB = *(const s16x8*)(Kg + (size_t)(kk0 + 32) * 1024);
  s16x8 vvA = *(const s16x8*)(Vg + (size_t)kk0 * 1024);
  s16x8 vvB = *(const s16x8*)(Vg + (size_t)(kk0 + 32) * 1024);
  storeKV(0, kvA, kvB, vvA, vvB);

  int cur = 0;
  for (int kt = 0; kt < 16; kt++) {
    if (kt < 15) {
      const size_t r0 = (size_t)((kt + 1) * 64 + kk0) * 1024;
      kvA = *(const s16x8*)(Kg + r0);
      kvB = *(const s16x8*)(Kg + r0 + 32 * 1024);
      vvA = *(const s16x8*)(Vg + r0);
      vvB = *(const s16x8*)(Vg + r0 + 32 * 1024);
    }
    __syncthreads();

    const short* Kc = &Klds[cur][0];
    const short* Vc = &Vtl[cur][0];

    f32x4 s_acc[2][4];
    #pragma unroll
    for (int i = 0; i < 2; i++)
      #pragma unroll
      for (int j = 0; j < 4; j++) s_acc[i][j] = (f32x4)0.0f;

    #pragma unroll
    for (int kf = 0; kf < 2; kf++) {
      s16x8 kfr[4];
      #pragma unroll
      for (int nf = 0; nf < 4; nf++)
        kfr[nf] = *(const s16x8*)(Kc + (nf * 16 + ln) * 64
                                     + (((kf * 4 + g) ^ (ln & 7)) * 8));
      #pragma unroll
      for (int mf = 0; mf < 2; mf++)
        #pragma unroll
        for (int nf = 0; nf < 4; nf++)
          s_acc[mf][nf] = __builtin_amdgcn_mfma_f32_16x16x32_bf16(
              asbf(qf[mf][kf]), asbf(kfr[nf]), s_acc[mf][nf], 0, 0, 0);
    }

    float smax[2][4];
    float worst = -1e30f;
    #pragma unroll
    for (int mf = 0; mf < 2; mf++)
      #pragma unroll
      for (int r = 0; r < 4; r++) {
        float mx = fmaxf(fmaxf(s_acc[mf][0][r], s_acc[mf][1][r]),
                         fmaxf(s_acc[mf][2][r], s_acc[mf][3][r]));
        mx = dpp_fmax16(mx);
        smax[mf][r] = mx;
        worst = fmaxf(worst, mx - m_run[mf][r]);
      }

    if (__all(worst <= 8.0f)) {
      #pragma unroll
      for (int mf = 0; mf < 2; mf++)
        #pragma unroll
        for (int r = 0; r < 4; r++) {
          float m0v = m_run[mf][r];
          float rs = 0.0f;
          #pragma unroll
          for (int nf = 0; nf < 4; nf++) {
            float pv = exp2f(s_acc[mf][nf][r] - m0v);
            s_acc[mf][nf][r] = pv;
            rs += pv;
          }
          l_run[mf][r] += rs;
        }
    } else {
      #pragma unroll
      for (int mf = 0; mf < 2; mf++)
        #pragma unroll
        for (int r = 0; r < 4; r++) {
          float mnew = fmaxf(m_run[mf][r], smax[mf][r]);
          float sc = exp2f(m_run[mf][r] - mnew);
          m_run[mf][r] = mnew;
          float rs = 0.0f;
          #pragma unroll
          for (int nf = 0; nf < 4; nf++) {
            float pv = exp2f(s_acc[mf][nf][r] - mnew);
            s_acc[mf][nf][r] = pv;
            rs += pv;
          }
          l_run[mf][r] = l_run[mf][r] * sc + rs;
          #pragma unroll
          for (int nf = 0; nf < 4; nf++) acc_o[mf][nf][r] *= sc;
        }
    }

    short* Pw = &Plds[w][0];
    #pragma unroll
    for (int mf = 0; mf < 2; mf++)
      #pragma unroll
      for (int nf = 0; nf < 4; nf++) {
        uint32_t p01, p23;
        asm("v_cvt_pk_bf16_f32 %0, %1, %2"
            : "=v"(p01) : "v"(s_acc[mf][nf][0]), "v"(s_acc[mf][nf][1]));
        asm("v_cvt_pk_bf16_f32 %0, %1, %2"
            : "=v"(p23) : "v"(s_acc[mf][nf][2]), "v"(s_acc[mf][nf][3]));
        int pb = (mf * 16 + g * 4) * 72 + ((nf * 16 + ln) ^ (g << 3));
        Pw[pb]       = (short)p01;
        Pw[pb + 72]  = (short)(p01 >> 16);
        Pw[pb + 144] = (short)p23;
        Pw[pb + 216] = (short)(p23 >> 16);
      }

    s16x8 pa[2][2], vbf[4][2];
    #pragma unroll
    for (int mf = 0; mf < 2; mf++)
      #pragma unroll
      for (int kf = 0; kf < 2; kf++)
        pa[mf][kf] = *(const s16x8*)(
            &Pw[(mf * 16 + ln) * 72 + (((kf * 4 + g) ^ (ln >> 2)) << 3)]);
    #pragma unroll
    for (int nf = 0; nf < 4; nf++)
      #pragma unroll
      for (int kf = 0; kf < 2; kf++) {
        int d  = nf * 16 + ln;
        int sw = (d & 7) ^ (d >> 3);
        vbf[nf][kf] = *(const s16x8*)(Vc + d * 64 + ((kf * 32 + g * 8) ^ (sw * 8)));
      }

    #pragma unroll
    for (int kf = 0; kf < 2; kf++)
      #pragma unroll
      for (int mf = 0; mf < 2; mf++)
        #pragma unroll
        for (int nf = 0; nf < 4; nf++)
          acc_o[mf][nf] = __builtin_amdgcn_mfma_f32_16x16x32_bf16(
              asbf(pa[mf][kf]), asbf(vbf[nf][kf]), acc_o[mf][nf], 0, 0, 0);

    if (kt < 15) {
      storeKV(cur ^ 1, kvA, kvB, vvA, vvB);
      cur ^= 1;
    }
  }

  #pragma unroll
  for (int mf = 0; mf < 2; mf++)
    #pragma unroll
    for (int r = 0; r < 4; r++) {
      float inv = 1.0f / dpp_fadd16(l_run[mf][r]);
      size_t row = rowbase + q0w + mf * 16 + g * 4 + r;
      #pragma unroll
      for (int nf = 0; nf < 4; nf++)
        CTX[row * 1024 + colbase + nf * 16 + ln] = f2bf(acc_o[mf][nf][r] * inv);
    }
}

// ---------------------------------------------------------------------------
extern "C" void kernel_launch(void* const* d_in, const int* in_sizes, int n_in,
                              void* d_out, int out_size, void* d_ws, size_t ws_size,
                              hipStream_t stream) {
  const float* query = (const float*)d_in[0];
  const float* key   = (const float*)d_in[1];
  const float* value = (const float*)d_in[2];
  const float* Wq = (const float*)d_in[3];
  const float* bq = (const float*)d_in[4];
  const float* Wk = (const float*)d_in[5];
  const float* bk = (const float*)d_in[6];
  const float* Wv = (const float*)d_in[7];
  const float* bv = (const float*)d_in[8];
  const float* Wo = (const float*)d_in[9];
  const float* bo = (const float*)d_in[10];

  const size_t E = (size_t)MTOT * 1024;
  const size_t need_b = (7 * E + 4ull * 1048576) * 2;   // ~125.8 MB (batched)
  const size_t need_s = (5 * E + 4ull * 1048576) * 2;   // ~92.3 MB  (middle)

  dim3 gg(MTOT / 128, HIDDEN / 128), bb(256);
  dim3 fg(BATCH * HEADS * (SEQ / 128));

  if (ws_size >= need_b) {
    short* Qb = (short*)d_ws;
    short* Kb = Qb + E;
    short* Vb = Kb + E;
    short* Cx = Vb + E;
    short* T0 = Cx + E;                 // 3 contiguous bf16 inputs (swizzled)
    short* Wb = T0 + 3 * E;             // 4x weights (swizzled)

    cvt_w<<<dim3(512, 4), bb, 0, stream>>>(Wq, Wk, Wv, Wo, Wb);
    cvt_x3<<<dim3(4096, 3), bb, 0, stream>>>(query, key, value, T0);
    gemm_qkv<<<dim3(MTOT / 128, HIDDEN / 128, 3), bb, 0, stream>>>(
        T0, Wb, bq, bk, bv, Qb, Kb, Vb);
    vtrans<<<dim3(16, 16, 8), bb, 0, stream>>>(Vb, T0);
    flash_attn<<<fg, bb, 0, stream>>>(Qb, Kb, T0, Cx);     // Cx swizzled
    gemm_bf16_dma<0><<<gg, bb, 0, stream>>>(Cx, Wb + 3 * 1048576, bo,
                                            (float*)d_out, 1.0f);
  } else if (ws_size >= need_s) {
    short* Qb = (short*)d_ws;
    short* Kb = Qb + E;
    short* Vb = Kb + E;
    short* Cx = Vb + E;
    short* T  = Cx + E;
    short* Wb = T  + E;

    cvt_w<<<dim3(512, 4), bb, 0, stream>>>(Wq, Wk, Wv, Wo, Wb);
    cvt_x<<<4096, bb, 0, stream>>>(query, T);
    gemm_bf16_dma<1><<<gg, bb, 0, stream>>>(T, Wb + 0 * 1048576, bq, Qb, QSCALE);
    cvt_x<<<4096, bb, 0, stream>>>(key, T);
    gemm_bf16_dma<2><<<gg, bb, 0, stream>>>(T, Wb + 1 * 1048576, bk, Kb, 1.0f);
    cvt_x<<<4096, bb, 0, stream>>>(value, T);
    gemm_bf16_dma<1><<<gg, bb, 0, stream>>>(T, Wb + 2 * 1048576, bv, Vb, 1.0f);
    vtrans<<<dim3(16, 16, 8), bb, 0, stream>>>(Vb, T);
    flash_attn<<<fg, bb, 0, stream>>>(Qb, Kb, T, Cx);      // Cx swizzled
    gemm_bf16_dma<0><<<gg, bb, 0, stream>>>(Cx, Wb + 3 * 1048576, bo,
                                            (float*)d_out, 1.0f);
  } else {
    short* Qb = (short*)d_ws;
    short* Kb = Qb + E;
    short* Vb = Kb + E;
    short* Cx = Vb + E;

    gemm_bt_bias<false, false><<<gg, bb, 0, stream>>>(query, Wq, bq, Qb, QSCALE);
    gemm_bt_bias<false, false><<<gg, bb, 0, stream>>>(key,   Wk, bk, Kb, 1.0f);
    gemm_bt_bias<false, false><<<gg, bb, 0, stream>>>(value, Wv, bv, Vb, 1.0f);
    flash_attn_fb<<<fg, bb, 0, stream>>>(Qb, Kb, Vb, Cx);
    gemm_bt_bias<true, true><<<gg, bb, 0, stream>>>(Cx, Wo, bo, (float*)d_out, 1.0f);
  }
}